// Round 18
// baseline (194.182 us; speedup 1.0000x reference)
//
#include <hip/hip_runtime.h>
#include <hip/hip_bf16.h>

typedef __bf16 bf16_t;
typedef __bf16 bf16x8 __attribute__((ext_vector_type(8)));
typedef float f32x4 __attribute__((ext_vector_type(4)));

#define MFMA16(a, b, c) __builtin_amdgcn_mfma_f32_16x16x32_bf16((a), (b), (c), 0, 0, 0)

__device__ __forceinline__ void gl_lds16(const bf16_t* g, bf16_t* l) {
  __builtin_amdgcn_global_load_lds(
      (const __attribute__((address_space(1))) void*)g,
      (__attribute__((address_space(3))) void*)l, 16, 0, 0);
}

__device__ __forceinline__ unsigned pack_bf16(float a, float b) {
  union { bf16_t h[2]; unsigned u; } c;
  c.h[0] = (bf16_t)a; c.h[1] = (bf16_t)b;
  return c.u;
}

// B=4, T=2048, D=512, H=8, DH=64 — hardcoded
// ---------------------------------------------------------------------------
// Merged prep: blocks [0,4096) convert x -> bf16; blocks [4096,4864) transpose
// the six weight matrices (fp32 -> bf16, LDS tile, coalesced both sides).
__global__ __launch_bounds__(256) void k_prep(
    const float* __restrict__ x, bf16_t* __restrict__ x_bf,
    const float* __restrict__ Wq, const float* __restrict__ Wk,
    const float* __restrict__ Wv, const float* __restrict__ Wo,
    const float* __restrict__ W1, const float* __restrict__ W2,
    bf16_t* __restrict__ WqkvT, bf16_t* __restrict__ WoT,
    bf16_t* __restrict__ W1T, bf16_t* __restrict__ W2T) {
  __shared__ float tile[64][65];
  int bid = blockIdx.x, tid = threadIdx.x;
  if (bid < 4096) {
    int i = bid * 256 + tid;  // 4096*256 == 8192*512/4 exactly
    float4 f = ((const float4*)x)[i];
    union { bf16_t h[4]; uint2 u; } cv;
    cv.h[0] = (bf16_t)f.x; cv.h[1] = (bf16_t)f.y;
    cv.h[2] = (bf16_t)f.z; cv.h[3] = (bf16_t)f.w;
    ((uint2*)x_bf)[i] = cv.u;
    return;
  }
  int t = bid - 4096;
  const float* W; bf16_t* WT; int K, N, idx, gx;
  if (t < 64)       { W = Wq; WT = WqkvT;                      K = 512;  N = 512;  idx = t;       gx = 8;  }
  else if (t < 128) { W = Wk; WT = WqkvT + (size_t)512 * 512;  K = 512;  N = 512;  idx = t - 64;  gx = 8;  }
  else if (t < 192) { W = Wv; WT = WqkvT + (size_t)1024 * 512; K = 512;  N = 512;  idx = t - 128; gx = 8;  }
  else if (t < 256) { W = Wo; WT = WoT;                        K = 512;  N = 512;  idx = t - 192; gx = 8;  }
  else if (t < 512) { W = W1; WT = W1T;                        K = 512;  N = 2048; idx = t - 256; gx = 8;  }
  else              { W = W2; WT = W2T;                        K = 2048; N = 512;  idx = t - 512; gx = 32; }
  int bk = (idx % gx) * 64, bn = (idx / gx) * 64;
  int tx = tid & 63, ty = tid >> 6;
  for (int i = ty; i < 64; i += 4)
    tile[i][tx] = W[(size_t)(bk + i) * N + bn + tx];
  __syncthreads();
  for (int i = ty; i < 64; i += 4)
    WT[(size_t)(bn + i) * K + bk + tx] = (bf16_t)tile[tx][i];
}

// ---------------------------------------------------------------------------
// C[M][N] = A[M][K] @ Bt[N][K]^T, bf16 in, fp32 accum. 2-phase double-buffered
// global_load_lds staging. MODE 0: fp32 C.
template <int MODE, int BM>
__global__ __launch_bounds__(256) void k_gemm_bt(
    const bf16_t* __restrict__ A, const bf16_t* __restrict__ Bt,
    float* __restrict__ Cf, bf16_t* __restrict__ Cb,
    int M, int N, int K, const float* __restrict__ coef) {
  __shared__ __align__(16) bf16_t As[2][BM * 32];
  __shared__ __align__(16) bf16_t Bs[2][128 * 32];
  constexpr int NF = (BM == 128) ? 4 : 2;
  int tid = threadIdx.x;
  int lane = tid & 63, wave = tid >> 6;
  int bm = blockIdx.x * BM, bn = blockIdx.y * 128;
  int wr = (BM == 128) ? (wave >> 1) * 64 : 0;
  int wc = (BM == 128) ? (wave & 1) * 64 : wave * 32;
  int lr = lane & 15, lk = (lane >> 4) * 8;
  int srow = tid >> 2, scol = (tid & 3) * 8;

  f32x4 zero = {0.f, 0.f, 0.f, 0.f};
  f32x4 acc[4][NF];
#pragma unroll
  for (int m = 0; m < 4; ++m)
#pragma unroll
    for (int n = 0; n < NF; ++n) acc[m][n] = zero;

  const bf16_t* pA = A + (size_t)(bm + srow) * K + scol;
  const bf16_t* pB = Bt + (size_t)(bn + srow) * K + scol;

  auto STAGE = [&](int buf, int k0) {
    bf16_t* lA = &As[buf][tid * 8];
    bf16_t* lB = &Bs[buf][tid * 8];
    gl_lds16(pA + k0, lA);
    if (BM == 128) gl_lds16(pA + (size_t)64 * K + k0, lA + 2048);
    gl_lds16(pB + k0, lB);
    gl_lds16(pB + (size_t)64 * K + k0, lB + 2048);
  };

  STAGE(0, 0);
  __syncthreads();
  int buf = 0;
  for (int k0 = 0; k0 < K; k0 += 32) {
    if (k0 + 32 < K) STAGE(buf ^ 1, k0 + 32);
    bf16x8 a[4], b[NF];
#pragma unroll
    for (int m = 0; m < 4; ++m) a[m] = *(const bf16x8*)&As[buf][(wr + m * 16 + lr) * 32 + lk];
#pragma unroll
    for (int n = 0; n < NF; ++n) b[n] = *(const bf16x8*)&Bs[buf][(wc + n * 16 + lr) * 32 + lk];
    __builtin_amdgcn_s_setprio(1);
#pragma unroll
    for (int m = 0; m < 4; ++m)
#pragma unroll
      for (int n = 0; n < NF; ++n)
        acc[m][n] = MFMA16(a[m], b[n], acc[m][n]);
    __builtin_amdgcn_s_setprio(0);
    __syncthreads();
    buf ^= 1;
  }

  int rbase = (lane >> 4) * 4;
#pragma unroll
  for (int m = 0; m < 4; ++m) {
#pragma unroll
    for (int n = 0; n < NF; ++n) {
#pragma unroll
      for (int r = 0; r < 4; ++r) {
        int gm = bm + wr + m * 16 + rbase + r;
        int gn = bn + wc + n * 16 + lr;
        Cf[(size_t)gm * N + gn] = acc[m][n][r];
      }
    }
  }
}

// ---------------------------------------------------------------------------
// 8-phase 256x256 GEMM template (T3+T4), K=512 (BK=64 as two 32-halves).
// LDS = 2 slots x {A,B} x 2 kh x [256][32] bf16 = 128 KB (dynamic). 8 waves
// (2M x 4N), wave output 128x64, acc[8][4]. Each phase: 8 ds_read_b128 + one
// half-tile DMA -> raw s_barrier -> 16 MFMA -> barrier; counted vmcnt(6) at
// odd phases only (never 0 in the loop). K accumulation order identical to
// the 2-phase kernel. MODE 4: GELU -> bf16 C[.][2048]. MODE 5: fused QKV
// scatter (Q pre-scaled 1/8, K pre-XOR-swizzled, V gl_lds-linear permuted).
template <int MODE>
__global__ __launch_bounds__(512, 2) void k_gemm8(
    const bf16_t* __restrict__ A, const bf16_t* __restrict__ Bt,
    bf16_t* __restrict__ Cb, bf16_t* __restrict__ Cb2,
    bf16_t* __restrict__ Cb3, const float* __restrict__ coef) {
  extern __shared__ __align__(16) bf16_t ldsraw[];  // 131072 bytes
  int tid = threadIdx.x;
  int lane = tid & 63, wave = tid >> 6;
  int wm = wave >> 2, wn = wave & 3;
  int lr = lane & 15, lg = lane >> 4;
  int bm = blockIdx.x * 256, bn = blockIdx.y * 256;

  f32x4 zero = {0.f, 0.f, 0.f, 0.f};
  f32x4 acc[8][4];
#pragma unroll
  for (int a = 0; a < 8; ++a)
#pragma unroll
    for (int n = 0; n < 4; ++n) acc[a][n] = zero;

  int srow = tid >> 2, scol = (tid & 3) * 8;
  const bf16_t* gA = A + (size_t)(bm + srow) * 512 + scol;
  const bf16_t* gB = Bt + (size_t)(bn + srow) * 512 + scol;

  auto LBASE = [&](int slot, int op, int kh) -> bf16_t* {
    return ldsraw + (size_t)((((slot << 1) | op) << 1) | kh) * 8192;
  };
  auto STG = [&](int slot, int op, int kh, int kt) {
    if (kt >= 8) return;
    bf16_t* dst = LBASE(slot, op, kh) + tid * 8;
    const bf16_t* src = (op ? gB : gA) + kt * 64 + kh * 32;
    gl_lds16(src, dst);
    gl_lds16(src + (size_t)128 * 512, dst + 4096);
  };

  auto PH = [&](int slot, int kh, int qm, int sS, int sOp, int sKh, int sT, bool vm) {
    bf16x8 af[4], bb[4];
    const bf16_t* Abase = LBASE(slot, 0, kh);
    const bf16_t* Bbase = LBASE(slot, 1, kh);
#pragma unroll
    for (int mf = 0; mf < 4; ++mf) {
      int r = wm * 128 + qm * 64 + mf * 16 + lr;
      af[mf] = *(const bf16x8*)&Abase[r * 32 + lg * 8];
    }
#pragma unroll
    for (int nf = 0; nf < 4; ++nf) {
      int r = wn * 64 + nf * 16 + lr;
      bb[nf] = *(const bf16x8*)&Bbase[r * 32 + lg * 8];
    }
    STG(sS, sOp, sKh, sT);
    if (vm) __asm__ volatile("s_waitcnt vmcnt(6)" ::: "memory");
    __asm__ volatile("" ::: "memory");
    __builtin_amdgcn_s_barrier();
    __asm__ volatile("" ::: "memory");
    __builtin_amdgcn_s_setprio(1);
#pragma unroll
    for (int mf = 0; mf < 4; ++mf)
#pragma unroll
      for (int nf = 0; nf < 4; ++nf)
        acc[qm * 4 + mf][nf] = MFMA16(af[mf], bb[nf], acc[qm * 4 + mf][nf]);
    __builtin_amdgcn_s_setprio(0);
    __asm__ volatile("" ::: "memory");
    __builtin_amdgcn_s_barrier();
    __asm__ volatile("" ::: "memory");
  };

  // prologue: tile0 full + tile1 kh0; counted wait
  STG(0, 0, 0, 0); STG(0, 1, 0, 0); STG(0, 0, 1, 0); STG(0, 1, 1, 0);
  STG(1, 0, 0, 1); STG(1, 1, 0, 1);
  __asm__ volatile("s_waitcnt vmcnt(8)" ::: "memory");
  __builtin_amdgcn_s_barrier();
  __asm__ volatile("" ::: "memory");

#pragma unroll
  for (int i = 0; i < 4; ++i) {
    int t1 = 2 * i + 1;
    PH(0, 0, 0, 1, 0, 1, t1, false);
    PH(0, 0, 1, 1, 1, 1, t1, true);
    PH(0, 1, 0, 0, 0, 0, t1 + 1, false);
    PH(0, 1, 1, 0, 1, 0, t1 + 1, true);
    PH(1, 0, 0, 0, 0, 1, t1 + 1, false);
    PH(1, 0, 1, 0, 1, 1, t1 + 1, true);
    PH(1, 1, 0, 1, 0, 0, t1 + 2, false);
    PH(1, 1, 1, 1, 1, 0, t1 + 2, true);
  }

  // epilogue
  float c8[8];
  if (MODE == 4) {
#pragma unroll
    for (int q = 0; q < 8; ++q) c8[q] = coef[q];
  }
#pragma unroll
  for (int am = 0; am < 8; ++am) {
    int qm = am >> 2, mf = am & 3;
#pragma unroll
    for (int nf = 0; nf < 4; ++nf)
#pragma unroll
      for (int rr = 0; rr < 4; ++rr) {
        int gm = bm + wm * 128 + qm * 64 + mf * 16 + lg * 4 + rr;
        int gn = bn + wn * 64 + nf * 16 + lr;
        float v = acc[am][nf][rr];
        if (MODE == 4) {
          float xx = fminf(fmaxf(v, -4.f), 4.f);
          float pw = 1.f, pp = c8[0];
#pragma unroll
          for (int q2 = 1; q2 < 8; ++q2) { pw *= xx; pp += c8[q2] * pw; }
          Cb[(size_t)gm * 2048 + gn] = (bf16_t)pp;
        } else {  // 5: fused QKV scatter with attention-ready layouts
          int mat = gn >> 9, col = gn & 511;
          int b_ = gm >> 11, t_ = gm & 2047, h_ = col >> 6, d_ = col & 63;
          if (mat == 0) {
            Cb[(((size_t)b_ * 8 + h_) * 2048 + t_) * 64 + d_] = (bf16_t)(v * 0.125f);
          } else if (mat == 1) {
            int dsw = d_ ^ ((t_ & 7) << 3);
            Cb2[(((size_t)b_ * 8 + h_) * 2048 + t_) * 64 + dsw] = (bf16_t)v;
          } else {
            int tw = t_ & 63;
            int j = (((tw >> 2) & 3) << 1) | ((tw >> 4) & 1);
            int phys = (((tw & 32) << 1) + (j << 3) + ((tw & 3) << 1)) ^ ((d_ & 7) << 4);
            size_t e = ((((size_t)b_ * 8 + h_) * 64 + d_) * 4096 +
                        (size_t)(t_ >> 6) * 128 + phys) >> 1;
            Cb3[e] = (bf16_t)v;
          }
        }
      }
  }
}

// ---------------------------------------------------------------------------
// SINGLE-PASS attention, SPLIT-K (KS=2). QBLK=128, 4 waves, j=2 reuse,
// K/V 2-deep DMA rings, ONE barrier per kt, Horner-only softmax (clamp
// provably dead), rsum on the MFMA pipe. bf16 o-partials + fp32 rsum partials.
__global__ __launch_bounds__(256, 4) void k_attn(
    const bf16_t* __restrict__ qb, const bf16_t* __restrict__ kb,
    const bf16_t* __restrict__ vtb, bf16_t* __restrict__ part,
    float* __restrict__ rsb, const float* __restrict__ exp_c) {
  __shared__ __align__(16) bf16_t Ks[2][64 * 64];
  __shared__ __align__(16) bf16_t Vs[2][64 * 64];
  int tid = threadIdx.x, lane = tid & 63, wave = tid >> 6;
  int b0 = blockIdx.x;
  int bid = (b0 & 7) * 128 + (b0 >> 3);  // XCD-chunked (1024 % 8 == 0)
  int ks = bid & 1, qt = (bid >> 1) & 15, bh = bid >> 5;
  int kt0 = ks * 16;
  const size_t bho = (size_t)bh * (2048 * 64);
  const bf16_t* Q = qb + bho + (size_t)qt * 128 * 64;  // pre-scaled by 1/8
  const bf16_t* Kp = kb + bho;   // rows pre-XOR-swizzled
  const bf16_t* Vp = vtb + bho;  // gl_lds-linear permuted [64 dh][2048 t]
  int lr = lane & 15, lg = lane >> 4;

  bf16x8 qa[2][2];
#pragma unroll
  for (int j = 0; j < 2; ++j)
#pragma unroll
    for (int h = 0; h < 2; ++h)
      qa[j][h] = *(const bf16x8*)&Q[(wave * 32 + j * 16 + lr) * 64 + h * 32 + lg * 8];

  float ec[7];
#pragma unroll
  for (int i = 0; i < 7; ++i) ec[i] = exp_c[i];

  union { unsigned u[4]; bf16x8 v; } ones;
#pragma unroll
  for (int i = 0; i < 4; ++i) ones.u[i] = 0x3f803f80u;  // bf16 1.0 x2

  int offA[4], offB[4];
#pragma unroll
  for (int n = 0; n < 4; ++n) {
    int row = n * 16 + lr, sw = (row & 7) << 4;
    offA[n] = (row * 128 + lg * 16) ^ sw;
    offB[n] = (row * 128 + 64 + lg * 16) ^ sw;
  }

  auto STAGE_K = [&](int buf, int kt) {
    bf16_t* lk = &Ks[buf][tid * 8];
    const bf16_t* gk = Kp + (size_t)kt * 4096 + tid * 8;
    gl_lds16(gk, lk);
    gl_lds16(gk + 2048, lk + 2048);
  };
  auto STAGE_V = [&](int buf, int kt) {
    bf16_t* lv = &Vs[buf][tid * 8];
    const bf16_t* gv = Vp + (size_t)(tid >> 3) * 2048 + kt * 64 + (tid & 7) * 8;
    gl_lds16(gv, lv);
    gl_lds16(gv + (size_t)32 * 2048, lv + 2048);
  };

  f32x4 zero = {0.f, 0.f, 0.f, 0.f};
  f32x4 oacc[2][4], oacc_s[2];
#pragma unroll
  for (int j = 0; j < 2; ++j) {
#pragma unroll
    for (int n = 0; n < 4; ++n) oacc[j][n] = zero;
    oacc_s[j] = zero;
  }

  STAGE_K(0, kt0);
  STAGE_V(0, kt0);
  __syncthreads();

  for (int lt = 0; lt < 16; ++lt) {
    if (lt < 15) {
      STAGE_K((lt + 1) & 1, kt0 + lt + 1);
      STAGE_V((lt + 1) & 1, kt0 + lt + 1);
    }
    const char* kbase = (const char*)Ks[lt & 1];
    const char* vbase = (const char*)Vs[lt & 1];
    f32x4 s[2][4];
    __builtin_amdgcn_s_setprio(1);
#pragma unroll
    for (int n = 0; n < 4; ++n) {
      bf16x8 kb0 = *(const bf16x8*)(kbase + offA[n]);
      bf16x8 kb1 = *(const bf16x8*)(kbase + offB[n]);
#pragma unroll
      for (int j = 0; j < 2; ++j)
        s[j][n] = MFMA16(kb1, qa[j][1], MFMA16(kb0, qa[j][0], zero));
    }
    __builtin_amdgcn_s_setprio(0);
    union { unsigned u[4]; bf16x8 v; } pa[2][2];
#pragma unroll
    for (int j = 0; j < 2; ++j) {
      unsigned pk[4][2];
#pragma unroll
      for (int n = 0; n < 4; ++n) {
        float pf[4];
#pragma unroll
        for (int r = 0; r < 4; ++r) {
          float xv = s[j][n][r];  // scores pre-scaled via Q*0.125
          float p = ec[6];
#pragma unroll
          for (int i = 5; i >= 0; --i) p = __builtin_fmaf(p, xv, ec[i]);
          pf[r] = p;
        }
        pk[n][0] = pack_bf16(pf[0], pf[1]);
        pk[n][1] = pack_bf16(pf[2], pf[3]);
      }
      pa[j][0].u[0] = pk[0][0]; pa[j][0].u[1] = pk[0][1];
      pa[j][0].u[2] = pk[1][0]; pa[j][0].u[3] = pk[1][1];
      pa[j][1].u[0] = pk[2][0]; pa[j][1].u[1] = pk[2][1];
      pa[j][1].u[2] = pk[3][0]; pa[j][1].u[3] = pk[3][1];
    }
    __builtin_amdgcn_s_setprio(1);
#pragma unroll
    for (int dd = 0; dd < 4; ++dd) {
      bf16x8 v0 = *(const bf16x8*)(vbase + offA[dd]);
      bf16x8 v1 = *(const bf16x8*)(vbase + offB[dd]);
#pragma unroll
      for (int j = 0; j < 2; ++j)
        oacc[j][dd] = MFMA16(pa[j][1].v, v1, MFMA16(pa[j][0].v, v0, oacc[j][dd]));
    }
#pragma unroll
    for (int j = 0; j < 2; ++j)
      oacc_s[j] = MFMA16(pa[j][1].v, ones.v, MFMA16(pa[j][0].v, ones.v, oacc_s[j]));
    __builtin_amdgcn_s_setprio(0);
    __syncthreads();
  }

  bf16_t* pp = part + (size_t)ks * (8192 * 512);
  int b_ = bh >> 3, h_ = bh & 7;
#pragma unroll
  for (int j = 0; j < 2; ++j) {
#pragma unroll
    for (int dd = 0; dd < 4; ++dd)
#pragma unroll
      for (int r = 0; r < 4; ++r) {
        int t_ = qt * 128 + wave * 32 + j * 16 + lg * 4 + r;
        int d_ = dd * 16 + lr;
        pp[(((size_t)b_ * 2048 + t_) * 8 + h_) * 64 + d_] = (bf16_t)oacc[j][dd][r];
      }
    if (lr == 0) {
#pragma unroll
      for (int r = 0; r < 4; ++r) {
        int t_ = qt * 128 + wave * 32 + j * 16 + lg * 4 + r;
        rsb[ks * 65536 + ((b_ * 2048 + t_) * 8 + h_)] = oacc_s[j][r];
      }
    }
  }
}

// ---------------------------------------------------------------------------
// Combine split-K partials: o = (p0+p1)/(r0+r1), bf16 in/out.
__global__ __launch_bounds__(256) void k_combine(
    const bf16_t* __restrict__ part, const float* __restrict__ rsb,
    bf16_t* __restrict__ ob) {
  int gid = blockIdx.x * 256 + threadIdx.x;
  int row = gid >> 3;
  float r = rsb[row] + rsb[65536 + row];
  bf16x8 a = ((const bf16x8*)part)[gid];
  bf16x8 b = ((const bf16x8*)(part + (size_t)8192 * 512))[gid];
  bf16x8 o;
#pragma unroll
  for (int i = 0; i < 8; ++i)
    o[i] = (bf16_t)(((float)a[i] + (float)b[i]) / r);
  ((bf16x8*)ob)[gid] = o;
}

// ---------------------------------------------------------------------------
// Fused residual + LayerNorm (replicates Newton rsqrt exactly: 3 iters from
// 0.5). AB=0: residual input xa is fp32; AB=1: xa is bf16.
template <int AB>
__global__ __launch_bounds__(256) void k_ln(
    const void* __restrict__ xav, const float* __restrict__ xb,
    const float* __restrict__ gamma, const float* __restrict__ beta,
    float* __restrict__ outf, bf16_t* __restrict__ outb) {
  int row = blockIdx.x * 4 + (threadIdx.x >> 6);
  int lane = threadIdx.x & 63;
  float xa[8];
  if (AB == 0) {
    const float* pa = (const float*)xav + (size_t)row * 512;
    float4 a0 = ((const float4*)pa)[lane];
    float4 a1 = ((const float4*)pa)[lane + 64];
    xa[0] = a0.x; xa[1] = a0.y; xa[2] = a0.z; xa[3] = a0.w;
    xa[4] = a1.x; xa[5] = a1.y; xa[6] = a1.z; xa[7] = a1.w;
  } else {
    const bf16_t* pa = (const bf16_t*)xav + (size_t)row * 512;
    union { uint2 u; bf16_t h[4]; } c0, c1;
    c0.u = ((const uint2*)pa)[lane];
    c1.u = ((const uint2*)pa)[lane + 64];
#pragma unroll
    for (int i = 0; i < 4; ++i) { xa[i] = (float)c0.h[i]; xa[4 + i] = (float)c1.h[i]; }
  }
  const float* pb = xb + (size_t)row * 512;
  float4 b0 = ((const float4*)pb)[lane];
  float4 b1 = ((const float4*)pb)[lane + 64];
  float x[8] = {xa[0] + b0.x, xa[1] + b0.y, xa[2] + b0.z, xa[3] + b0.w,
                xa[4] + b1.x, xa[5] + b1.y, xa[6] + b1.z, xa[7] + b1.w};
  float s = 0.f, sq = 0.f;
#pragma unroll
  for (int i = 0; i < 8; ++i) { s += x[i]; sq += x[i] * x[i]; }
#pragma unroll
  for (int off = 1; off < 64; off <<= 1) {
    s += __shfl_xor(s, off);
    sq += __shfl_xor(sq, off);
  }
  float mean = s * (1.f / 512.f);
  float var = sq * (1.f / 512.f) - mean * mean;
  float v = var + 1e-5f;
  float y = 0.5f;
#pragma unroll
  for (int it = 0; it < 3; ++it) y = y * (3.0f - v * y * y) * 0.5f;

  float4 g0 = ((const float4*)gamma)[lane];
  float4 g1 = ((const float4*)gamma)[lane + 64];
  float4 e0 = ((const float4*)beta)[lane];
  float4 e1 = ((const float4*)beta)[lane + 64];
  float o[8];
  o[0] = (x[0] - mean) * y * g0.x + e0.x;
  o[1] = (x[1] - mean) * y * g0.y + e0.y;
  o[2] = (x[2] - mean) * y * g0.z + e0.z;
  o[3] = (x[3] - mean) * y * g0.w + e0.w;
  o[4] = (x[4] - mean) * y * g1.x + e1.x;
  o[5] = (x[5] - mean) * y * g1.y + e1.y;
  o[6] = (x[6] - mean) * y * g1.z + e1.z;
  o[7] = (x[7] - mean) * y * g1.w + e1.w;
  if (outf) {
    float* po = outf + (size_t)row * 512;
    ((float4*)po)[lane]      = make_float4(o[0], o[1], o[2], o[3]);
    ((float4*)po)[lane + 64] = make_float4(o[4], o[5], o[6], o[7]);
  }
  if (outb) {
    bf16_t* pq = outb + (size_t)row * 512;
    union { bf16_t h[4]; uint2 u; } c0, c1;
    c0.h[0] = (bf16_t)o[0]; c0.h[1] = (bf16_t)o[1]; c0.h[2] = (bf16_t)o[2]; c0.h[3] = (bf16_t)o[3];
    c1.h[0] = (bf16_t)o[4]; c1.h[1] = (bf16_t)o[5]; c1.h[2] = (bf16_t)o[6]; c1.h[3] = (bf16_t)o[7];
    ((uint2*)pq)[lane]      = c0.u;
    ((uint2*)pq)[lane + 64] = c1.u;
  }
}

// ---------------------------------------------------------------------------
extern "C" void kernel_launch(void* const* d_in, const int* in_sizes, int n_in,
                              void* d_out, int out_size, void* d_ws, size_t ws_size,
                              hipStream_t stream) {
  const float* x      = (const float*)d_in[0];
  const float* Wq     = (const float*)d_in[1];
  const float* Wk     = (const float*)d_in[2];
  const float* Wv     = (const float*)d_in[3];
  const float* Wo     = (const float*)d_in[4];
  const float* W1     = (const float*)d_in[5];
  const float* W2     = (const float*)d_in[6];
  const float* g1     = (const float*)d_in[7];
  const float* b1     = (const float*)d_in[8];
  const float* g2     = (const float*)d_in[9];
  const float* b2     = (const float*)d_in[10];
  const float* gelu_c = (const float*)d_in[11];
  const float* exp_c  = (const float*)d_in[12];

  const int M = 8192;  // B*T
  const size_t actBF = (size_t)M * 512 * 2;
  char* p = (char*)d_ws;
  auto carve = [&](size_t bytes) {
    void* r = (void*)p;
    p += (bytes + 255) & ~(size_t)255;
    return r;
  };
  bf16_t* x_bf   = (bf16_t*)carve(actBF);
  bf16_t* q_bf   = (bf16_t*)carve(actBF);
  bf16_t* k_bf   = (bf16_t*)carve(actBF);
  bf16_t* vT_bf  = (bf16_t*)carve(actBF);
  bf16_t* o_bf   = (bf16_t*)carve(actBF);
  bf16_t* h_bf   = (bf16_t*)carve(actBF);
  bf16_t* WqkvT  = (bf16_t*)carve((size_t)1536 * 512 * 2);
  bf16_t* WoT    = (bf16_t*)carve(512 * 512 * 2);
  bf16_t* W1T    = (bf16_t*)carve(512 * 2048 * 2);
  bf16_t* W2T    = (bf16_t*)carve(512 * 2048 * 2);
  bf16_t* g_bf   = (bf16_t*)carve((size_t)M * 2048 * 2);  // 32 MiB
  float*  proj   = (float*)carve((size_t)M * 512 * 4);
  float*  f2     = proj;  // proj dead after LN1; FFN2 output aliases it
  bf16_t* part   = (bf16_t*)g_bf;   // split-K o-partials (dead until FFN1)
  float*  rsb    = (float*)proj;    // rsum partials (dead until Wo writes)

  // merged prep: cvt (4096 blocks) + 6 transposes (768 blocks)
  k_prep<<<4864, 256, 0, stream>>>(x, x_bf, Wq, Wk, Wv, Wo, W1, W2,
                                   WqkvT, WoT, W1T, W2T);

  // fused QKV projection, 8-phase 256x256 (192 blocks, 128 KB LDS)
  k_gemm8<5><<<dim3(32, 6), 512, 131072, stream>>>(
      x_bf, WqkvT, q_bf, k_bf, vT_bf, nullptr);

  // attention (single pass, split-K x2 -> 1024 blocks, bf16 partials)
  k_attn<<<1024, 256, 0, stream>>>(q_bf, k_bf, vT_bf, part, rsb, exp_c);

  // combine partials -> o_bf
  k_combine<<<2048, 256, 0, stream>>>(part, rsb, o_bf);

  // output projection
  k_gemm_bt<0, 64><<<dim3(128, 4), 256, 0, stream>>>(
      o_bf, WoT, proj, nullptr, M, 512, 512, nullptr);

  // LN1: h = LN(x + proj) -> bf16
  k_ln<0><<<2048, 256, 0, stream>>>(x, proj, g1, b1, nullptr, h_bf);

  // FFN1: gelu(h @ W1) -> bf16, 8-phase 256x256 (256 blocks, 128 KB LDS)
  k_gemm8<4><<<dim3(32, 8), 512, 131072, stream>>>(
      h_bf, W1T, g_bf, nullptr, nullptr, gelu_c);

  // FFN2
  k_gemm_bt<0, 64><<<dim3(128, 4), 256, 0, stream>>>(
      g_bf, W2T, f2, nullptr, M, 512, 2048, nullptr);

  // LN2: out = LN(h + ffn), h read as bf16
  k_ln<1><<<2048, 256, 0, stream>>>(h_bf, f2, g2, b2, (float*)d_out, nullptr);
}

// Round 19
// 182.760 us; speedup vs baseline: 1.0625x; 1.0625x over previous
//
#include <hip/hip_runtime.h>
#include <hip/hip_bf16.h>

typedef __bf16 bf16_t;
typedef __bf16 bf16x8 __attribute__((ext_vector_type(8)));
typedef float f32x4 __attribute__((ext_vector_type(4)));

#define MFMA16(a, b, c) __builtin_amdgcn_mfma_f32_16x16x32_bf16((a), (b), (c), 0, 0, 0)

__device__ __forceinline__ void gl_lds16(const bf16_t* g, bf16_t* l) {
  __builtin_amdgcn_global_load_lds(
      (const __attribute__((address_space(1))) void*)g,
      (__attribute__((address_space(3))) void*)l, 16, 0, 0);
}

__device__ __forceinline__ unsigned pack_bf16(float a, float b) {
  union { bf16_t h[2]; unsigned u; } c;
  c.h[0] = (bf16_t)a; c.h[1] = (bf16_t)b;
  return c.u;
}

// B=4, T=2048, D=512, H=8, DH=64 — hardcoded
// ---------------------------------------------------------------------------
// Merged prep: blocks [0,4096) convert x -> bf16; blocks [4096,4864) transpose
// the six weight matrices (fp32 -> bf16, LDS tile, coalesced both sides).
__global__ __launch_bounds__(256) void k_prep(
    const float* __restrict__ x, bf16_t* __restrict__ x_bf,
    const float* __restrict__ Wq, const float* __restrict__ Wk,
    const float* __restrict__ Wv, const float* __restrict__ Wo,
    const float* __restrict__ W1, const float* __restrict__ W2,
    bf16_t* __restrict__ WqkvT, bf16_t* __restrict__ WoT,
    bf16_t* __restrict__ W1T, bf16_t* __restrict__ W2T) {
  __shared__ float tile[64][65];
  int bid = blockIdx.x, tid = threadIdx.x;
  if (bid < 4096) {
    int i = bid * 256 + tid;  // 4096*256 == 8192*512/4 exactly
    float4 f = ((const float4*)x)[i];
    union { bf16_t h[4]; uint2 u; } cv;
    cv.h[0] = (bf16_t)f.x; cv.h[1] = (bf16_t)f.y;
    cv.h[2] = (bf16_t)f.z; cv.h[3] = (bf16_t)f.w;
    ((uint2*)x_bf)[i] = cv.u;
    return;
  }
  int t = bid - 4096;
  const float* W; bf16_t* WT; int K, N, idx, gx;
  if (t < 64)       { W = Wq; WT = WqkvT;                      K = 512;  N = 512;  idx = t;       gx = 8;  }
  else if (t < 128) { W = Wk; WT = WqkvT + (size_t)512 * 512;  K = 512;  N = 512;  idx = t - 64;  gx = 8;  }
  else if (t < 192) { W = Wv; WT = WqkvT + (size_t)1024 * 512; K = 512;  N = 512;  idx = t - 128; gx = 8;  }
  else if (t < 256) { W = Wo; WT = WoT;                        K = 512;  N = 512;  idx = t - 192; gx = 8;  }
  else if (t < 512) { W = W1; WT = W1T;                        K = 512;  N = 2048; idx = t - 256; gx = 8;  }
  else              { W = W2; WT = W2T;                        K = 2048; N = 512;  idx = t - 512; gx = 32; }
  int bk = (idx % gx) * 64, bn = (idx / gx) * 64;
  int tx = tid & 63, ty = tid >> 6;
  for (int i = ty; i < 64; i += 4)
    tile[i][tx] = W[(size_t)(bk + i) * N + bn + tx];
  __syncthreads();
  for (int i = ty; i < 64; i += 4)
    WT[(size_t)(bn + i) * K + bk + tx] = (bf16_t)tile[tx][i];
}

// ---------------------------------------------------------------------------
// C[M][N] = A[M][K] @ Bt[N][K]^T, bf16 in, fp32 accum. 2-phase double-buffered
// global_load_lds staging.
// MODE 0: fp32 C    5: fused QKV scatter (Q pre-scaled by 1/8, K pre-XOR-
// swizzled, V in the gl_lds-linear permuted layout).
template <int MODE, int BM>
__global__ __launch_bounds__(256) void k_gemm_bt(
    const bf16_t* __restrict__ A, const bf16_t* __restrict__ Bt,
    float* __restrict__ Cf, bf16_t* __restrict__ Cb,
    bf16_t* __restrict__ Cb2, bf16_t* __restrict__ Cb3,
    int M, int N, int K, const float* __restrict__ coef) {
  __shared__ __align__(16) bf16_t As[2][BM * 32];
  __shared__ __align__(16) bf16_t Bs[2][128 * 32];
  constexpr int NF = (BM == 128) ? 4 : 2;
  int tid = threadIdx.x;
  int lane = tid & 63, wave = tid >> 6;
  int bm = blockIdx.x * BM, bn = blockIdx.y * 128;
  int wr = (BM == 128) ? (wave >> 1) * 64 : 0;
  int wc = (BM == 128) ? (wave & 1) * 64 : wave * 32;
  int lr = lane & 15, lk = (lane >> 4) * 8;
  int srow = tid >> 2, scol = (tid & 3) * 8;

  f32x4 zero = {0.f, 0.f, 0.f, 0.f};
  f32x4 acc[4][NF];
#pragma unroll
  for (int m = 0; m < 4; ++m)
#pragma unroll
    for (int n = 0; n < NF; ++n) acc[m][n] = zero;

  const bf16_t* pA = A + (size_t)(bm + srow) * K + scol;
  const bf16_t* pB = Bt + (size_t)(bn + srow) * K + scol;

  auto STAGE = [&](int buf, int k0) {
    bf16_t* lA = &As[buf][tid * 8];
    bf16_t* lB = &Bs[buf][tid * 8];
    gl_lds16(pA + k0, lA);
    if (BM == 128) gl_lds16(pA + (size_t)64 * K + k0, lA + 2048);
    gl_lds16(pB + k0, lB);
    gl_lds16(pB + (size_t)64 * K + k0, lB + 2048);
  };

  STAGE(0, 0);
  __syncthreads();
  int buf = 0;
  for (int k0 = 0; k0 < K; k0 += 32) {
    if (k0 + 32 < K) STAGE(buf ^ 1, k0 + 32);
    bf16x8 a[4], b[NF];
#pragma unroll
    for (int m = 0; m < 4; ++m) a[m] = *(const bf16x8*)&As[buf][(wr + m * 16 + lr) * 32 + lk];
#pragma unroll
    for (int n = 0; n < NF; ++n) b[n] = *(const bf16x8*)&Bs[buf][(wc + n * 16 + lr) * 32 + lk];
    __builtin_amdgcn_s_setprio(1);
#pragma unroll
    for (int m = 0; m < 4; ++m)
#pragma unroll
      for (int n = 0; n < NF; ++n)
        acc[m][n] = MFMA16(a[m], b[n], acc[m][n]);
    __builtin_amdgcn_s_setprio(0);
    __syncthreads();
    buf ^= 1;
  }

  int rbase = (lane >> 4) * 4;
#pragma unroll
  for (int m = 0; m < 4; ++m) {
#pragma unroll
    for (int n = 0; n < NF; ++n) {
#pragma unroll
      for (int r = 0; r < 4; ++r) {
        int gm = bm + wr + m * 16 + rbase + r;
        int gn = bn + wc + n * 16 + lr;
        float v = acc[m][n][r];
        if (MODE == 0) {
          Cf[(size_t)gm * N + gn] = v;
        } else {  // 5: fused QKV scatter with attention-ready layouts
          int mat = gn >> 9, col = gn & 511;
          int b_ = gm >> 11, t_ = gm & 2047, h_ = col >> 6, d_ = col & 63;
          if (mat == 0) {
            Cb[(((size_t)b_ * 8 + h_) * 2048 + t_) * 64 + d_] = (bf16_t)(v * 0.125f);
          } else if (mat == 1) {
            int dsw = d_ ^ ((t_ & 7) << 3);
            Cb2[(((size_t)b_ * 8 + h_) * 2048 + t_) * 64 + dsw] = (bf16_t)v;
          } else {
            int tw = t_ & 63;
            int j = (((tw >> 2) & 3) << 1) | ((tw >> 4) & 1);
            int phys = (((tw & 32) << 1) + (j << 3) + ((tw & 3) << 1)) ^ ((d_ & 7) << 4);
            size_t e = ((((size_t)b_ * 8 + h_) * 64 + d_) * 4096 +
                        (size_t)(t_ >> 6) * 128 + phys) >> 1;
            Cb3[e] = (bf16_t)v;
          }
        }
      }
    }
  }
}

// ---------------------------------------------------------------------------
// FFN1 as 8-phase 256x256 GEMM (T3+T4): C[8192][2048] = gelu(A[8192][512] @
// W1T[2048][512]^T). BK=64 split into two K-halves of 32; LDS = 2 slots x
// {A,B} x 2 kh x [256][32] bf16 = 128 KB (dynamic). 8 waves (2M x 4N), wave
// output 128x64, acc[8][4]. Each phase: 8 ds_read_b128 + one half DMA ->
// raw s_barrier -> 16 MFMA -> barrier; counted vmcnt(6) at odd phases only.
__global__ __launch_bounds__(512, 2) void k_ffn1(
    const bf16_t* __restrict__ A, const bf16_t* __restrict__ Bt,
    bf16_t* __restrict__ C, const float* __restrict__ coef) {
  extern __shared__ __align__(16) bf16_t ldsraw[];  // 131072 bytes
  int tid = threadIdx.x;
  int lane = tid & 63, wave = tid >> 6;
  int wm = wave >> 2, wn = wave & 3;
  int lr = lane & 15, lg = lane >> 4;
  int bm = blockIdx.x * 256, bn = blockIdx.y * 256;

  f32x4 zero = {0.f, 0.f, 0.f, 0.f};
  f32x4 acc[8][4];
#pragma unroll
  for (int a = 0; a < 8; ++a)
#pragma unroll
    for (int n = 0; n < 4; ++n) acc[a][n] = zero;

  int srow = tid >> 2, scol = (tid & 3) * 8;
  const bf16_t* gA = A + (size_t)(bm + srow) * 512 + scol;
  const bf16_t* gB = Bt + (size_t)(bn + srow) * 512 + scol;

  auto LBASE = [&](int slot, int op, int kh) -> bf16_t* {
    return ldsraw + (size_t)((((slot << 1) | op) << 1) | kh) * 8192;
  };
  auto STG = [&](int slot, int op, int kh, int kt) {
    if (kt >= 8) return;
    bf16_t* dst = LBASE(slot, op, kh) + tid * 8;
    const bf16_t* src = (op ? gB : gA) + kt * 64 + kh * 32;
    gl_lds16(src, dst);
    gl_lds16(src + (size_t)128 * 512, dst + 4096);
  };

  auto PH = [&](int slot, int kh, int qm, int sS, int sOp, int sKh, int sT, bool vm) {
    bf16x8 af[4], bb[4];
    const bf16_t* Abase = LBASE(slot, 0, kh);
    const bf16_t* Bbase = LBASE(slot, 1, kh);
#pragma unroll
    for (int mf = 0; mf < 4; ++mf) {
      int r = wm * 128 + qm * 64 + mf * 16 + lr;
      af[mf] = *(const bf16x8*)&Abase[r * 32 + lg * 8];
    }
#pragma unroll
    for (int nf = 0; nf < 4; ++nf) {
      int r = wn * 64 + nf * 16 + lr;
      bb[nf] = *(const bf16x8*)&Bbase[r * 32 + lg * 8];
    }
    STG(sS, sOp, sKh, sT);
    if (vm) __asm__ volatile("s_waitcnt vmcnt(6)" ::: "memory");
    __asm__ volatile("" ::: "memory");
    __builtin_amdgcn_s_barrier();
    __asm__ volatile("" ::: "memory");
    __builtin_amdgcn_s_setprio(1);
#pragma unroll
    for (int mf = 0; mf < 4; ++mf)
#pragma unroll
      for (int nf = 0; nf < 4; ++nf)
        acc[qm * 4 + mf][nf] = MFMA16(af[mf], bb[nf], acc[qm * 4 + mf][nf]);
    __builtin_amdgcn_s_setprio(0);
    __asm__ volatile("" ::: "memory");
    __builtin_amdgcn_s_barrier();
    __asm__ volatile("" ::: "memory");
  };

  // prologue: tile0 full + tile1 kh0; counted wait
  STG(0, 0, 0, 0); STG(0, 1, 0, 0); STG(0, 0, 1, 0); STG(0, 1, 1, 0);
  STG(1, 0, 0, 1); STG(1, 1, 0, 1);
  __asm__ volatile("s_waitcnt vmcnt(8)" ::: "memory");
  __builtin_amdgcn_s_barrier();
  __asm__ volatile("" ::: "memory");

#pragma unroll
  for (int i = 0; i < 4; ++i) {
    int t1 = 2 * i + 1;
    PH(0, 0, 0, 1, 0, 1, t1, false);
    PH(0, 0, 1, 1, 1, 1, t1, true);
    PH(0, 1, 0, 0, 0, 0, t1 + 1, false);
    PH(0, 1, 1, 0, 1, 0, t1 + 1, true);
    PH(1, 0, 0, 0, 0, 1, t1 + 1, false);
    PH(1, 0, 1, 0, 1, 1, t1 + 1, true);
    PH(1, 1, 0, 1, 0, 0, t1 + 2, false);
    PH(1, 1, 1, 1, 1, 0, t1 + 2, true);
  }

  // epilogue: iterative-power GELU poly (matches reference eval order), bf16
  float c8[8];
#pragma unroll
  for (int q = 0; q < 8; ++q) c8[q] = coef[q];
#pragma unroll
  for (int am = 0; am < 8; ++am) {
    int qm = am >> 2, mf = am & 3;
#pragma unroll
    for (int nf = 0; nf < 4; ++nf)
#pragma unroll
      for (int rr = 0; rr < 4; ++rr) {
        int row = bm + wm * 128 + qm * 64 + mf * 16 + lg * 4 + rr;
        int col = bn + wn * 64 + nf * 16 + lr;
        float v = acc[am][nf][rr];
        float xx = fminf(fmaxf(v, -4.f), 4.f);
        float pw = 1.f, pp = c8[0];
#pragma unroll
        for (int q2 = 1; q2 < 8; ++q2) { pw *= xx; pp += c8[q2] * pw; }
        C[(size_t)row * 2048 + col] = (bf16_t)pp;
      }
  }
}

// ---------------------------------------------------------------------------
// SINGLE-PASS attention, SPLIT-K (KS=2). QBLK=128, 4 waves, j=2 reuse,
// K/V 2-deep DMA rings, ONE barrier per kt, Horner-only softmax (clamp
// provably dead), rsum on the MFMA pipe. bf16 o-partials + fp32 rsum partials.
__global__ __launch_bounds__(256, 4) void k_attn(
    const bf16_t* __restrict__ qb, const bf16_t* __restrict__ kb,
    const bf16_t* __restrict__ vtb, bf16_t* __restrict__ part,
    float* __restrict__ rsb, const float* __restrict__ exp_c) {
  __shared__ __align__(16) bf16_t Ks[2][64 * 64];
  __shared__ __align__(16) bf16_t Vs[2][64 * 64];
  int tid = threadIdx.x, lane = tid & 63, wave = tid >> 6;
  int b0 = blockIdx.x;
  int bid = (b0 & 7) * 128 + (b0 >> 3);  // XCD-chunked (1024 % 8 == 0)
  int ks = bid & 1, qt = (bid >> 1) & 15, bh = bid >> 5;
  int kt0 = ks * 16;
  const size_t bho = (size_t)bh * (2048 * 64);
  const bf16_t* Q = qb + bho + (size_t)qt * 128 * 64;  // pre-scaled by 1/8
  const bf16_t* Kp = kb + bho;   // rows pre-XOR-swizzled
  const bf16_t* Vp = vtb + bho;  // gl_lds-linear permuted [64 dh][2048 t]
  int lr = lane & 15, lg = lane >> 4;

  bf16x8 qa[2][2];
#pragma unroll
  for (int j = 0; j < 2; ++j)
#pragma unroll
    for (int h = 0; h < 2; ++h)
      qa[j][h] = *(const bf16x8*)&Q[(wave * 32 + j * 16 + lr) * 64 + h * 32 + lg * 8];

  float ec[7];
#pragma unroll
  for (int i = 0; i < 7; ++i) ec[i] = exp_c[i];

  union { unsigned u[4]; bf16x8 v; } ones;
#pragma unroll
  for (int i = 0; i < 4; ++i) ones.u[i] = 0x3f803f80u;  // bf16 1.0 x2

  int offA[4], offB[4];
#pragma unroll
  for (int n = 0; n < 4; ++n) {
    int row = n * 16 + lr, sw = (row & 7) << 4;
    offA[n] = (row * 128 + lg * 16) ^ sw;
    offB[n] = (row * 128 + 64 + lg * 16) ^ sw;
  }

  auto STAGE_K = [&](int buf, int kt) {
    bf16_t* lk = &Ks[buf][tid * 8];
    const bf16_t* gk = Kp + (size_t)kt * 4096 + tid * 8;
    gl_lds16(gk, lk);
    gl_lds16(gk + 2048, lk + 2048);
  };
  auto STAGE_V = [&](int buf, int kt) {
    bf16_t* lv = &Vs[buf][tid * 8];
    const bf16_t* gv = Vp + (size_t)(tid >> 3) * 2048 + kt * 64 + (tid & 7) * 8;
    gl_lds16(gv, lv);
    gl_lds16(gv + (size_t)32 * 2048, lv + 2048);
  };

  f32x4 zero = {0.f, 0.f, 0.f, 0.f};
  f32x4 oacc[2][4], oacc_s[2];
#pragma unroll
  for (int j = 0; j < 2; ++j) {
#pragma unroll
    for (int n = 0; n < 4; ++n) oacc[j][n] = zero;
    oacc_s[j] = zero;
  }

  STAGE_K(0, kt0);
  STAGE_V(0, kt0);
  __syncthreads();

  for (int lt = 0; lt < 16; ++lt) {
    if (lt < 15) {
      STAGE_K((lt + 1) & 1, kt0 + lt + 1);
      STAGE_V((lt + 1) & 1, kt0 + lt + 1);
    }
    const char* kbase = (const char*)Ks[lt & 1];
    const char* vbase = (const char*)Vs[lt & 1];
    f32x4 s[2][4];
    __builtin_amdgcn_s_setprio(1);
#pragma unroll
    for (int n = 0; n < 4; ++n) {
      bf16x8 kb0 = *(const bf16x8*)(kbase + offA[n]);
      bf16x8 kb1 = *(const bf16x8*)(kbase + offB[n]);
#pragma unroll
      for (int j = 0; j < 2; ++j)
        s[j][n] = MFMA16(kb1, qa[j][1], MFMA16(kb0, qa[j][0], zero));
    }
    __builtin_amdgcn_s_setprio(0);
    union { unsigned u[4]; bf16x8 v; } pa[2][2];
#pragma unroll
    for (int j = 0; j < 2; ++j) {
      unsigned pk[4][2];
#pragma unroll
      for (int n = 0; n < 4; ++n) {
        float pf[4];
#pragma unroll
        for (int r = 0; r < 4; ++r) {
          float xv = s[j][n][r];  // scores pre-scaled via Q*0.125
          float p = ec[6];
#pragma unroll
          for (int i = 5; i >= 0; --i) p = __builtin_fmaf(p, xv, ec[i]);
          pf[r] = p;
        }
        pk[n][0] = pack_bf16(pf[0], pf[1]);
        pk[n][1] = pack_bf16(pf[2], pf[3]);
      }
      pa[j][0].u[0] = pk[0][0]; pa[j][0].u[1] = pk[0][1];
      pa[j][0].u[2] = pk[1][0]; pa[j][0].u[3] = pk[1][1];
      pa[j][1].u[0] = pk[2][0]; pa[j][1].u[1] = pk[2][1];
      pa[j][1].u[2] = pk[3][0]; pa[j][1].u[3] = pk[3][1];
    }
    __builtin_amdgcn_s_setprio(1);
#pragma unroll
    for (int dd = 0; dd < 4; ++dd) {
      bf16x8 v0 = *(const bf16x8*)(vbase + offA[dd]);
      bf16x8 v1 = *(const bf16x8*)(vbase + offB[dd]);
#pragma unroll
      for (int j = 0; j < 2; ++j)
        oacc[j][dd] = MFMA16(pa[j][1].v, v1, MFMA16(pa[j][0].v, v0, oacc[j][dd]));
    }
#pragma unroll
    for (int j = 0; j < 2; ++j)
      oacc_s[j] = MFMA16(pa[j][1].v, ones.v, MFMA16(pa[j][0].v, ones.v, oacc_s[j]));
    __builtin_amdgcn_s_setprio(0);
    __syncthreads();
  }

  bf16_t* pp = part + (size_t)ks * (8192 * 512);
  int b_ = bh >> 3, h_ = bh & 7;
#pragma unroll
  for (int j = 0; j < 2; ++j) {
#pragma unroll
    for (int dd = 0; dd < 4; ++dd)
#pragma unroll
      for (int r = 0; r < 4; ++r) {
        int t_ = qt * 128 + wave * 32 + j * 16 + lg * 4 + r;
        int d_ = dd * 16 + lr;
        pp[(((size_t)b_ * 2048 + t_) * 8 + h_) * 64 + d_] = (bf16_t)oacc[j][dd][r];
      }
    if (lr == 0) {
#pragma unroll
      for (int r = 0; r < 4; ++r) {
        int t_ = qt * 128 + wave * 32 + j * 16 + lg * 4 + r;
        rsb[ks * 65536 + ((b_ * 2048 + t_) * 8 + h_)] = oacc_s[j][r];
      }
    }
  }
}

// ---------------------------------------------------------------------------
// Combine split-K partials: o = (p0+p1)/(r0+r1), bf16 in/out.
__global__ __launch_bounds__(256) void k_combine(
    const bf16_t* __restrict__ part, const float* __restrict__ rsb,
    bf16_t* __restrict__ ob) {
  int gid = blockIdx.x * 256 + threadIdx.x;
  int row = gid >> 3;
  float r = rsb[row] + rsb[65536 + row];
  bf16x8 a = ((const bf16x8*)part)[gid];
  bf16x8 b = ((const bf16x8*)(part + (size_t)8192 * 512))[gid];
  bf16x8 o;
#pragma unroll
  for (int i = 0; i < 8; ++i)
    o[i] = (bf16_t)(((float)a[i] + (float)b[i]) / r);
  ((bf16x8*)ob)[gid] = o;
}

// ---------------------------------------------------------------------------
// Fused residual + LayerNorm (replicates Newton rsqrt exactly: 3 iters from
// 0.5). AB=0: residual input xa is fp32; AB=1: xa is bf16.
template <int AB>
__global__ __launch_bounds__(256) void k_ln(
    const void* __restrict__ xav, const float* __restrict__ xb,
    const float* __restrict__ gamma, const float* __restrict__ beta,
    float* __restrict__ outf, bf16_t* __restrict__ outb) {
  int row = blockIdx.x * 4 + (threadIdx.x >> 6);
  int lane = threadIdx.x & 63;
  float xa[8];
  if (AB == 0) {
    const float* pa = (const float*)xav + (size_t)row * 512;
    float4 a0 = ((const float4*)pa)[lane];
    float4 a1 = ((const float4*)pa)[lane + 64];
    xa[0] = a0.x; xa[1] = a0.y; xa[2] = a0.z; xa[3] = a0.w;
    xa[4] = a1.x; xa[5] = a1.y; xa[6] = a1.z; xa[7] = a1.w;
  } else {
    const bf16_t* pa = (const bf16_t*)xav + (size_t)row * 512;
    union { uint2 u; bf16_t h[4]; } c0, c1;
    c0.u = ((const uint2*)pa)[lane];
    c1.u = ((const uint2*)pa)[lane + 64];
#pragma unroll
    for (int i = 0; i < 4; ++i) { xa[i] = (float)c0.h[i]; xa[4 + i] = (float)c1.h[i]; }
  }
  const float* pb = xb + (size_t)row * 512;
  float4 b0 = ((const float4*)pb)[lane];
  float4 b1 = ((const float4*)pb)[lane + 64];
  float x[8] = {xa[0] + b0.x, xa[1] + b0.y, xa[2] + b0.z, xa[3] + b0.w,
                xa[4] + b1.x, xa[5] + b1.y, xa[6] + b1.z, xa[7] + b1.w};
  float s = 0.f, sq = 0.f;
#pragma unroll
  for (int i = 0; i < 8; ++i) { s += x[i]; sq += x[i] * x[i]; }
#pragma unroll
  for (int off = 1; off < 64; off <<= 1) {
    s += __shfl_xor(s, off);
    sq += __shfl_xor(sq, off);
  }
  float mean = s * (1.f / 512.f);
  float var = sq * (1.f / 512.f) - mean * mean;
  float v = var + 1e-5f;
  float y = 0.5f;
#pragma unroll
  for (int it = 0; it < 3; ++it) y = y * (3.0f - v * y * y) * 0.5f;

  float4 g0 = ((const float4*)gamma)[lane];
  float4 g1 = ((const float4*)gamma)[lane + 64];
  float4 e0 = ((const float4*)beta)[lane];
  float4 e1 = ((const float4*)beta)[lane + 64];
  float o[8];
  o[0] = (x[0] - mean) * y * g0.x + e0.x;
  o[1] = (x[1] - mean) * y * g0.y + e0.y;
  o[2] = (x[2] - mean) * y * g0.z + e0.z;
  o[3] = (x[3] - mean) * y * g0.w + e0.w;
  o[4] = (x[4] - mean) * y * g1.x + e1.x;
  o[5] = (x[5] - mean) * y * g1.y + e1.y;
  o[6] = (x[6] - mean) * y * g1.z + e1.z;
  o[7] = (x[7] - mean) * y * g1.w + e1.w;
  if (outf) {
    float* po = outf + (size_t)row * 512;
    ((float4*)po)[lane]      = make_float4(o[0], o[1], o[2], o[3]);
    ((float4*)po)[lane + 64] = make_float4(o[4], o[5], o[6], o[7]);
  }
  if (outb) {
    bf16_t* pq = outb + (size_t)row * 512;
    union { bf16_t h[4]; uint2 u; } c0, c1;
    c0.h[0] = (bf16_t)o[0]; c0.h[1] = (bf16_t)o[1]; c0.h[2] = (bf16_t)o[2]; c0.h[3] = (bf16_t)o[3];
    c1.h[0] = (bf16_t)o[4]; c1.h[1] = (bf16_t)o[5]; c1.h[2] = (bf16_t)o[6]; c1.h[3] = (bf16_t)o[7];
    ((uint2*)pq)[lane]      = c0.u;
    ((uint2*)pq)[lane + 64] = c1.u;
  }
}

// ---------------------------------------------------------------------------
extern "C" void kernel_launch(void* const* d_in, const int* in_sizes, int n_in,
                              void* d_out, int out_size, void* d_ws, size_t ws_size,
                              hipStream_t stream) {
  const float* x      = (const float*)d_in[0];
  const float* Wq     = (const float*)d_in[1];
  const float* Wk     = (const float*)d_in[2];
  const float* Wv     = (const float*)d_in[3];
  const float* Wo     = (const float*)d_in[4];
  const float* W1     = (const float*)d_in[5];
  const float* W2     = (const float*)d_in[6];
  const float* g1     = (const float*)d_in[7];
  const float* b1     = (const float*)d_in[8];
  const float* g2     = (const float*)d_in[9];
  const float* b2     = (const float*)d_in[10];
  const float* gelu_c = (const float*)d_in[11];
  const float* exp_c  = (const float*)d_in[12];

  const int M = 8192;  // B*T
  const size_t actBF = (size_t)M * 512 * 2;
  char* p = (char*)d_ws;
  auto carve = [&](size_t bytes) {
    void* r = (void*)p;
    p += (bytes + 255) & ~(size_t)255;
    return r;
  };
  bf16_t* x_bf   = (bf16_t*)carve(actBF);
  bf16_t* q_bf   = (bf16_t*)carve(actBF);
  bf16_t* k_bf   = (bf16_t*)carve(actBF);
  bf16_t* vT_bf  = (bf16_t*)carve(actBF);
  bf16_t* o_bf   = (bf16_t*)carve(actBF);
  bf16_t* h_bf   = (bf16_t*)carve(actBF);
  bf16_t* WqkvT  = (bf16_t*)carve((size_t)1536 * 512 * 2);
  bf16_t* WoT    = (bf16_t*)carve(512 * 512 * 2);
  bf16_t* W1T    = (bf16_t*)carve(512 * 2048 * 2);
  bf16_t* W2T    = (bf16_t*)carve(512 * 2048 * 2);
  bf16_t* g_bf   = (bf16_t*)carve((size_t)M * 2048 * 2);  // 32 MiB
  float*  proj   = (float*)carve((size_t)M * 512 * 4);
  float*  f2     = proj;  // proj dead after LN1; FFN2 output aliases it
  bf16_t* part   = (bf16_t*)g_bf;   // split-K o-partials (dead until FFN1)
  float*  rsb    = (float*)proj;    // rsum partials (dead until Wo writes)

  // merged prep: cvt (4096 blocks) + 6 transposes (768 blocks)
  k_prep<<<4864, 256, 0, stream>>>(x, x_bf, Wq, Wk, Wv, Wo, W1, W2,
                                   WqkvT, WoT, W1T, W2T);

  // fused QKV projection, 2-phase (768 blocks — best measured config)
  k_gemm_bt<5, 128><<<dim3(64, 12), 256, 0, stream>>>(
      x_bf, WqkvT, nullptr, q_bf, k_bf, vT_bf, M, 1536, 512, nullptr);

  // attention (single pass, split-K x2 -> 1024 blocks, bf16 partials)
  k_attn<<<1024, 256, 0, stream>>>(q_bf, k_bf, vT_bf, part, rsb, exp_c);

  // combine partials -> o_bf
  k_combine<<<2048, 256, 0, stream>>>(part, rsb, o_bf);

  // output projection
  k_gemm_bt<0, 64><<<dim3(128, 4), 256, 0, stream>>>(
      o_bf, WoT, proj, nullptr, nullptr, nullptr, M, 512, 512, nullptr);

  // LN1: h = LN(x + proj) -> bf16
  k_ln<0><<<2048, 256, 0, stream>>>(x, proj, g1, b1, nullptr, h_bf);

  // FFN1: gelu(h @ W1) -> bf16, 8-phase 256x256 (256 blocks, 128 KB LDS)
  k_ffn1<<<dim3(32, 8), 512, 131072, stream>>>(h_bf, W1T, g_bf, gelu_c);

  // FFN2
  k_gemm_bt<0, 64><<<dim3(128, 4), 256, 0, stream>>>(
      g_bf, W2T, f2, nullptr, nullptr, nullptr, M, 512, 2048, nullptr);

  // LN2: out = LN(h + ffn), h read as bf16
  k_ln<1><<<2048, 256, 0, stream>>>(h_bf, f2, g2, b2, (float*)d_out, nullptr);
}

// Round 20
// 180.045 us; speedup vs baseline: 1.0785x; 1.0151x over previous
//
#include <hip/hip_runtime.h>
#include <hip/hip_bf16.h>

typedef __bf16 bf16_t;
typedef __bf16 bf16x8 __attribute__((ext_vector_type(8)));
typedef float f32x4 __attribute__((ext_vector_type(4)));

#define MFMA16(a, b, c) __builtin_amdgcn_mfma_f32_16x16x32_bf16((a), (b), (c), 0, 0, 0)

__device__ __forceinline__ void gl_lds16(const bf16_t* g, bf16_t* l) {
  __builtin_amdgcn_global_load_lds(
      (const __attribute__((address_space(1))) void*)g,
      (__attribute__((address_space(3))) void*)l, 16, 0, 0);
}

__device__ __forceinline__ unsigned pack_bf16(float a, float b) {
  union { bf16_t h[2]; unsigned u; } c;
  c.h[0] = (bf16_t)a; c.h[1] = (bf16_t)b;
  return c.u;
}

// B=4, T=2048, D=512, H=8, DH=64 — hardcoded
// ---------------------------------------------------------------------------
// Merged prep: blocks [0,4096) convert x -> bf16; blocks [4096,4864) transpose
// the six weight matrices (fp32 -> bf16, LDS tile, coalesced both sides).
__global__ __launch_bounds__(256) void k_prep(
    const float* __restrict__ x, bf16_t* __restrict__ x_bf,
    const float* __restrict__ Wq, const float* __restrict__ Wk,
    const float* __restrict__ Wv, const float* __restrict__ Wo,
    const float* __restrict__ W1, const float* __restrict__ W2,
    bf16_t* __restrict__ WqkvT, bf16_t* __restrict__ WoT,
    bf16_t* __restrict__ W1T, bf16_t* __restrict__ W2T) {
  __shared__ float tile[64][65];
  int bid = blockIdx.x, tid = threadIdx.x;
  if (bid < 4096) {
    int i = bid * 256 + tid;  // 4096*256 == 8192*512/4 exactly
    float4 f = ((const float4*)x)[i];
    union { bf16_t h[4]; uint2 u; } cv;
    cv.h[0] = (bf16_t)f.x; cv.h[1] = (bf16_t)f.y;
    cv.h[2] = (bf16_t)f.z; cv.h[3] = (bf16_t)f.w;
    ((uint2*)x_bf)[i] = cv.u;
    return;
  }
  int t = bid - 4096;
  const float* W; bf16_t* WT; int K, N, idx, gx;
  if (t < 64)       { W = Wq; WT = WqkvT;                      K = 512;  N = 512;  idx = t;       gx = 8;  }
  else if (t < 128) { W = Wk; WT = WqkvT + (size_t)512 * 512;  K = 512;  N = 512;  idx = t - 64;  gx = 8;  }
  else if (t < 192) { W = Wv; WT = WqkvT + (size_t)1024 * 512; K = 512;  N = 512;  idx = t - 128; gx = 8;  }
  else if (t < 256) { W = Wo; WT = WoT;                        K = 512;  N = 512;  idx = t - 192; gx = 8;  }
  else if (t < 512) { W = W1; WT = W1T;                        K = 512;  N = 2048; idx = t - 256; gx = 8;  }
  else              { W = W2; WT = W2T;                        K = 2048; N = 512;  idx = t - 512; gx = 32; }
  int bk = (idx % gx) * 64, bn = (idx / gx) * 64;
  int tx = tid & 63, ty = tid >> 6;
  for (int i = ty; i < 64; i += 4)
    tile[i][tx] = W[(size_t)(bk + i) * N + bn + tx];
  __syncthreads();
  for (int i = ty; i < 64; i += 4)
    WT[(size_t)(bn + i) * K + bk + tx] = (bf16_t)tile[tx][i];
}

// ---------------------------------------------------------------------------
// C[M][N] = A[M][K] @ Bt[N][K]^T, bf16 in, fp32 accum. 2-phase double-buffered
// global_load_lds staging.
// MODE 1: bf16 C    5: fused QKV scatter (Q pre-scaled by 1/8, K pre-XOR-
// swizzled, V in the gl_lds-linear permuted layout).
template <int MODE, int BM>
__global__ __launch_bounds__(256) void k_gemm_bt(
    const bf16_t* __restrict__ A, const bf16_t* __restrict__ Bt,
    bf16_t* __restrict__ Cb, bf16_t* __restrict__ Cb2,
    bf16_t* __restrict__ Cb3,
    int M, int N, int K, const float* __restrict__ coef) {
  __shared__ __align__(16) bf16_t As[2][BM * 32];
  __shared__ __align__(16) bf16_t Bs[2][128 * 32];
  constexpr int NF = (BM == 128) ? 4 : 2;
  int tid = threadIdx.x;
  int lane = tid & 63, wave = tid >> 6;
  int bm = blockIdx.x * BM, bn = blockIdx.y * 128;
  int wr = (BM == 128) ? (wave >> 1) * 64 : 0;
  int wc = (BM == 128) ? (wave & 1) * 64 : wave * 32;
  int lr = lane & 15, lk = (lane >> 4) * 8;
  int srow = tid >> 2, scol = (tid & 3) * 8;

  f32x4 zero = {0.f, 0.f, 0.f, 0.f};
  f32x4 acc[4][NF];
#pragma unroll
  for (int m = 0; m < 4; ++m)
#pragma unroll
    for (int n = 0; n < NF; ++n) acc[m][n] = zero;

  const bf16_t* pA = A + (size_t)(bm + srow) * K + scol;
  const bf16_t* pB = Bt + (size_t)(bn + srow) * K + scol;

  auto STAGE = [&](int buf, int k0) {
    bf16_t* lA = &As[buf][tid * 8];
    bf16_t* lB = &Bs[buf][tid * 8];
    gl_lds16(pA + k0, lA);
    if (BM == 128) gl_lds16(pA + (size_t)64 * K + k0, lA + 2048);
    gl_lds16(pB + k0, lB);
    gl_lds16(pB + (size_t)64 * K + k0, lB + 2048);
  };

  STAGE(0, 0);
  __syncthreads();
  int buf = 0;
  for (int k0 = 0; k0 < K; k0 += 32) {
    if (k0 + 32 < K) STAGE(buf ^ 1, k0 + 32);
    bf16x8 a[4], b[NF];
#pragma unroll
    for (int m = 0; m < 4; ++m) a[m] = *(const bf16x8*)&As[buf][(wr + m * 16 + lr) * 32 + lk];
#pragma unroll
    for (int n = 0; n < NF; ++n) b[n] = *(const bf16x8*)&Bs[buf][(wc + n * 16 + lr) * 32 + lk];
    __builtin_amdgcn_s_setprio(1);
#pragma unroll
    for (int m = 0; m < 4; ++m)
#pragma unroll
      for (int n = 0; n < NF; ++n)
        acc[m][n] = MFMA16(a[m], b[n], acc[m][n]);
    __builtin_amdgcn_s_setprio(0);
    __syncthreads();
    buf ^= 1;
  }

  int rbase = (lane >> 4) * 4;
#pragma unroll
  for (int m = 0; m < 4; ++m) {
#pragma unroll
    for (int n = 0; n < NF; ++n) {
#pragma unroll
      for (int r = 0; r < 4; ++r) {
        int gm = bm + wr + m * 16 + rbase + r;
        int gn = bn + wc + n * 16 + lr;
        float v = acc[m][n][r];
        if (MODE == 1) {
          Cb[(size_t)gm * N + gn] = (bf16_t)v;
        } else {  // 5: fused QKV scatter with attention-ready layouts
          int mat = gn >> 9, col = gn & 511;
          int b_ = gm >> 11, t_ = gm & 2047, h_ = col >> 6, d_ = col & 63;
          if (mat == 0) {
            Cb[(((size_t)b_ * 8 + h_) * 2048 + t_) * 64 + d_] = (bf16_t)(v * 0.125f);
          } else if (mat == 1) {
            int dsw = d_ ^ ((t_ & 7) << 3);
            Cb2[(((size_t)b_ * 8 + h_) * 2048 + t_) * 64 + dsw] = (bf16_t)v;
          } else {
            int tw = t_ & 63;
            int j = (((tw >> 2) & 3) << 1) | ((tw >> 4) & 1);
            int phys = (((tw & 32) << 1) + (j << 3) + ((tw & 3) << 1)) ^ ((d_ & 7) << 4);
            size_t e = ((((size_t)b_ * 8 + h_) * 64 + d_) * 4096 +
                        (size_t)(t_ >> 6) * 128 + phys) >> 1;
            Cb3[e] = (bf16_t)v;
          }
        }
      }
    }
  }
}

// ---------------------------------------------------------------------------
// FFN1 as 8-phase 256x256 GEMM (T3+T4): C[8192][2048] = gelu(A[8192][512] @
// W1T[2048][512]^T). BK=64 split into two K-halves of 32; LDS = 2 slots x
// {A,B} x 2 kh x [256][32] bf16 = 128 KB (dynamic). 8 waves (2M x 4N), wave
// output 128x64, acc[8][4]. Each phase: 8 ds_read_b128 + one half DMA ->
// raw s_barrier -> 16 MFMA -> barrier; counted vmcnt(6) at odd phases only.
__global__ __launch_bounds__(512, 2) void k_ffn1(
    const bf16_t* __restrict__ A, const bf16_t* __restrict__ Bt,
    bf16_t* __restrict__ C, const float* __restrict__ coef) {
  extern __shared__ __align__(16) bf16_t ldsraw[];  // 131072 bytes
  int tid = threadIdx.x;
  int lane = tid & 63, wave = tid >> 6;
  int wm = wave >> 2, wn = wave & 3;
  int lr = lane & 15, lg = lane >> 4;
  int bm = blockIdx.x * 256, bn = blockIdx.y * 256;

  f32x4 zero = {0.f, 0.f, 0.f, 0.f};
  f32x4 acc[8][4];
#pragma unroll
  for (int a = 0; a < 8; ++a)
#pragma unroll
    for (int n = 0; n < 4; ++n) acc[a][n] = zero;

  int srow = tid >> 2, scol = (tid & 3) * 8;
  const bf16_t* gA = A + (size_t)(bm + srow) * 512 + scol;
  const bf16_t* gB = Bt + (size_t)(bn + srow) * 512 + scol;

  auto LBASE = [&](int slot, int op, int kh) -> bf16_t* {
    return ldsraw + (size_t)((((slot << 1) | op) << 1) | kh) * 8192;
  };
  auto STG = [&](int slot, int op, int kh, int kt) {
    if (kt >= 8) return;
    bf16_t* dst = LBASE(slot, op, kh) + tid * 8;
    const bf16_t* src = (op ? gB : gA) + kt * 64 + kh * 32;
    gl_lds16(src, dst);
    gl_lds16(src + (size_t)128 * 512, dst + 4096);
  };

  auto PH = [&](int slot, int kh, int qm, int sS, int sOp, int sKh, int sT, bool vm) {
    bf16x8 af[4], bb[4];
    const bf16_t* Abase = LBASE(slot, 0, kh);
    const bf16_t* Bbase = LBASE(slot, 1, kh);
#pragma unroll
    for (int mf = 0; mf < 4; ++mf) {
      int r = wm * 128 + qm * 64 + mf * 16 + lr;
      af[mf] = *(const bf16x8*)&Abase[r * 32 + lg * 8];
    }
#pragma unroll
    for (int nf = 0; nf < 4; ++nf) {
      int r = wn * 64 + nf * 16 + lr;
      bb[nf] = *(const bf16x8*)&Bbase[r * 32 + lg * 8];
    }
    STG(sS, sOp, sKh, sT);
    if (vm) __asm__ volatile("s_waitcnt vmcnt(6)" ::: "memory");
    __asm__ volatile("" ::: "memory");
    __builtin_amdgcn_s_barrier();
    __asm__ volatile("" ::: "memory");
    __builtin_amdgcn_s_setprio(1);
#pragma unroll
    for (int mf = 0; mf < 4; ++mf)
#pragma unroll
      for (int nf = 0; nf < 4; ++nf)
        acc[qm * 4 + mf][nf] = MFMA16(af[mf], bb[nf], acc[qm * 4 + mf][nf]);
    __builtin_amdgcn_s_setprio(0);
    __asm__ volatile("" ::: "memory");
    __builtin_amdgcn_s_barrier();
    __asm__ volatile("" ::: "memory");
  };

  // prologue: tile0 full + tile1 kh0; counted wait
  STG(0, 0, 0, 0); STG(0, 1, 0, 0); STG(0, 0, 1, 0); STG(0, 1, 1, 0);
  STG(1, 0, 0, 1); STG(1, 1, 0, 1);
  __asm__ volatile("s_waitcnt vmcnt(8)" ::: "memory");
  __builtin_amdgcn_s_barrier();
  __asm__ volatile("" ::: "memory");

#pragma unroll
  for (int i = 0; i < 4; ++i) {
    int t1 = 2 * i + 1;
    PH(0, 0, 0, 1, 0, 1, t1, false);
    PH(0, 0, 1, 1, 1, 1, t1, true);
    PH(0, 1, 0, 0, 0, 0, t1 + 1, false);
    PH(0, 1, 1, 0, 1, 0, t1 + 1, true);
    PH(1, 0, 0, 0, 0, 1, t1 + 1, false);
    PH(1, 0, 1, 0, 1, 1, t1 + 1, true);
    PH(1, 1, 0, 1, 0, 0, t1 + 2, false);
    PH(1, 1, 1, 1, 1, 0, t1 + 2, true);
  }

  // epilogue: iterative-power GELU poly (matches reference eval order), bf16
  float c8[8];
#pragma unroll
  for (int q = 0; q < 8; ++q) c8[q] = coef[q];
#pragma unroll
  for (int am = 0; am < 8; ++am) {
    int qm = am >> 2, mf = am & 3;
#pragma unroll
    for (int nf = 0; nf < 4; ++nf)
#pragma unroll
      for (int rr = 0; rr < 4; ++rr) {
        int row = bm + wm * 128 + qm * 64 + mf * 16 + lg * 4 + rr;
        int col = bn + wn * 64 + nf * 16 + lr;
        float v = acc[am][nf][rr];
        float xx = fminf(fmaxf(v, -4.f), 4.f);
        float pw = 1.f, pp = c8[0];
#pragma unroll
        for (int q2 = 1; q2 < 8; ++q2) { pw *= xx; pp += c8[q2] * pw; }
        C[(size_t)row * 2048 + col] = (bf16_t)pp;
      }
  }
}

// ---------------------------------------------------------------------------
// SINGLE-PASS attention, SPLIT-K (KS=2). QBLK=128, 4 waves, j=2 reuse,
// K/V 2-deep DMA rings, ONE barrier per kt, Horner-only softmax (clamp
// provably dead), rsum on the MFMA pipe. bf16 o-partials + fp32 rsum partials.
__global__ __launch_bounds__(256, 4) void k_attn(
    const bf16_t* __restrict__ qb, const bf16_t* __restrict__ kb,
    const bf16_t* __restrict__ vtb, bf16_t* __restrict__ part,
    float* __restrict__ rsb, const float* __restrict__ exp_c) {
  __shared__ __align__(16) bf16_t Ks[2][64 * 64];
  __shared__ __align__(16) bf16_t Vs[2][64 * 64];
  int tid = threadIdx.x, lane = tid & 63, wave = tid >> 6;
  int b0 = blockIdx.x;
  int bid = (b0 & 7) * 128 + (b0 >> 3);  // XCD-chunked (1024 % 8 == 0)
  int ks = bid & 1, qt = (bid >> 1) & 15, bh = bid >> 5;
  int kt0 = ks * 16;
  const size_t bho = (size_t)bh * (2048 * 64);
  const bf16_t* Q = qb + bho + (size_t)qt * 128 * 64;  // pre-scaled by 1/8
  const bf16_t* Kp = kb + bho;   // rows pre-XOR-swizzled
  const bf16_t* Vp = vtb + bho;  // gl_lds-linear permuted [64 dh][2048 t]
  int lr = lane & 15, lg = lane >> 4;

  bf16x8 qa[2][2];
#pragma unroll
  for (int j = 0; j < 2; ++j)
#pragma unroll
    for (int h = 0; h < 2; ++h)
      qa[j][h] = *(const bf16x8*)&Q[(wave * 32 + j * 16 + lr) * 64 + h * 32 + lg * 8];

  float ec[7];
#pragma unroll
  for (int i = 0; i < 7; ++i) ec[i] = exp_c[i];

  union { unsigned u[4]; bf16x8 v; } ones;
#pragma unroll
  for (int i = 0; i < 4; ++i) ones.u[i] = 0x3f803f80u;  // bf16 1.0 x2

  int offA[4], offB[4];
#pragma unroll
  for (int n = 0; n < 4; ++n) {
    int row = n * 16 + lr, sw = (row & 7) << 4;
    offA[n] = (row * 128 + lg * 16) ^ sw;
    offB[n] = (row * 128 + 64 + lg * 16) ^ sw;
  }

  auto STAGE_K = [&](int buf, int kt) {
    bf16_t* lk = &Ks[buf][tid * 8];
    const bf16_t* gk = Kp + (size_t)kt * 4096 + tid * 8;
    gl_lds16(gk, lk);
    gl_lds16(gk + 2048, lk + 2048);
  };
  auto STAGE_V = [&](int buf, int kt) {
    bf16_t* lv = &Vs[buf][tid * 8];
    const bf16_t* gv = Vp + (size_t)(tid >> 3) * 2048 + kt * 64 + (tid & 7) * 8;
    gl_lds16(gv, lv);
    gl_lds16(gv + (size_t)32 * 2048, lv + 2048);
  };

  f32x4 zero = {0.f, 0.f, 0.f, 0.f};
  f32x4 oacc[2][4], oacc_s[2];
#pragma unroll
  for (int j = 0; j < 2; ++j) {
#pragma unroll
    for (int n = 0; n < 4; ++n) oacc[j][n] = zero;
    oacc_s[j] = zero;
  }

  STAGE_K(0, kt0);
  STAGE_V(0, kt0);
  __syncthreads();

  for (int lt = 0; lt < 16; ++lt) {
    if (lt < 15) {
      STAGE_K((lt + 1) & 1, kt0 + lt + 1);
      STAGE_V((lt + 1) & 1, kt0 + lt + 1);
    }
    const char* kbase = (const char*)Ks[lt & 1];
    const char* vbase = (const char*)Vs[lt & 1];
    f32x4 s[2][4];
    __builtin_amdgcn_s_setprio(1);
#pragma unroll
    for (int n = 0; n < 4; ++n) {
      bf16x8 kb0 = *(const bf16x8*)(kbase + offA[n]);
      bf16x8 kb1 = *(const bf16x8*)(kbase + offB[n]);
#pragma unroll
      for (int j = 0; j < 2; ++j)
        s[j][n] = MFMA16(kb1, qa[j][1], MFMA16(kb0, qa[j][0], zero));
    }
    __builtin_amdgcn_s_setprio(0);
    union { unsigned u[4]; bf16x8 v; } pa[2][2];
#pragma unroll
    for (int j = 0; j < 2; ++j) {
      unsigned pk[4][2];
#pragma unroll
      for (int n = 0; n < 4; ++n) {
        float pf[4];
#pragma unroll
        for (int r = 0; r < 4; ++r) {
          float xv = s[j][n][r];  // scores pre-scaled via Q*0.125
          float p = ec[6];
#pragma unroll
          for (int i = 5; i >= 0; --i) p = __builtin_fmaf(p, xv, ec[i]);
          pf[r] = p;
        }
        pk[n][0] = pack_bf16(pf[0], pf[1]);
        pk[n][1] = pack_bf16(pf[2], pf[3]);
      }
      pa[j][0].u[0] = pk[0][0]; pa[j][0].u[1] = pk[0][1];
      pa[j][0].u[2] = pk[1][0]; pa[j][0].u[3] = pk[1][1];
      pa[j][1].u[0] = pk[2][0]; pa[j][1].u[1] = pk[2][1];
      pa[j][1].u[2] = pk[3][0]; pa[j][1].u[3] = pk[3][1];
    }
    __builtin_amdgcn_s_setprio(1);
#pragma unroll
    for (int dd = 0; dd < 4; ++dd) {
      bf16x8 v0 = *(const bf16x8*)(vbase + offA[dd]);
      bf16x8 v1 = *(const bf16x8*)(vbase + offB[dd]);
#pragma unroll
      for (int j = 0; j < 2; ++j)
        oacc[j][dd] = MFMA16(pa[j][1].v, v1, MFMA16(pa[j][0].v, v0, oacc[j][dd]));
    }
#pragma unroll
    for (int j = 0; j < 2; ++j)
      oacc_s[j] = MFMA16(pa[j][1].v, ones.v, MFMA16(pa[j][0].v, ones.v, oacc_s[j]));
    __builtin_amdgcn_s_setprio(0);
    __syncthreads();
  }

  bf16_t* pp = part + (size_t)ks * (8192 * 512);
  int b_ = bh >> 3, h_ = bh & 7;
#pragma unroll
  for (int j = 0; j < 2; ++j) {
#pragma unroll
    for (int dd = 0; dd < 4; ++dd)
#pragma unroll
      for (int r = 0; r < 4; ++r) {
        int t_ = qt * 128 + wave * 32 + j * 16 + lg * 4 + r;
        int d_ = dd * 16 + lr;
        pp[(((size_t)b_ * 2048 + t_) * 8 + h_) * 64 + d_] = (bf16_t)oacc[j][dd][r];
      }
    if (lr == 0) {
#pragma unroll
      for (int r = 0; r < 4; ++r) {
        int t_ = qt * 128 + wave * 32 + j * 16 + lg * 4 + r;
        rsb[ks * 65536 + ((b_ * 2048 + t_) * 8 + h_)] = oacc_s[j][r];
      }
    }
  }
}

// ---------------------------------------------------------------------------
// Combine split-K partials: o = (p0+p1)/(r0+r1), bf16 in/out.
__global__ __launch_bounds__(256) void k_combine(
    const bf16_t* __restrict__ part, const float* __restrict__ rsb,
    bf16_t* __restrict__ ob) {
  int gid = blockIdx.x * 256 + threadIdx.x;
  int row = gid >> 3;
  float r = rsb[row] + rsb[65536 + row];
  bf16x8 a = ((const bf16x8*)part)[gid];
  bf16x8 b = ((const bf16x8*)(part + (size_t)8192 * 512))[gid];
  bf16x8 o;
#pragma unroll
  for (int i = 0; i < 8; ++i)
    o[i] = (bf16_t)(((float)a[i] + (float)b[i]) / r);
  ((bf16x8*)ob)[gid] = o;
}

// ---------------------------------------------------------------------------
// Fused residual + LayerNorm (replicates Newton rsqrt exactly: 3 iters from
// 0.5). AB/BB select fp32(0)/bf16(1) for the two inputs.
template <int AB, int BB>
__global__ __launch_bounds__(256) void k_ln(
    const void* __restrict__ xav, const void* __restrict__ xbv,
    const float* __restrict__ gamma, const float* __restrict__ beta,
    float* __restrict__ outf, bf16_t* __restrict__ outb) {
  int row = blockIdx.x * 4 + (threadIdx.x >> 6);
  int lane = threadIdx.x & 63;
  float xa[8], xb[8];
  if (AB == 0) {
    const float* pa = (const float*)xav + (size_t)row * 512;
    float4 a0 = ((const float4*)pa)[lane];
    float4 a1 = ((const float4*)pa)[lane + 64];
    xa[0] = a0.x; xa[1] = a0.y; xa[2] = a0.z; xa[3] = a0.w;
    xa[4] = a1.x; xa[5] = a1.y; xa[6] = a1.z; xa[7] = a1.w;
  } else {
    const bf16_t* pa = (const bf16_t*)xav + (size_t)row * 512;
    union { uint2 u; bf16_t h[4]; } c0, c1;
    c0.u = ((const uint2*)pa)[lane];
    c1.u = ((const uint2*)pa)[lane + 64];
#pragma unroll
    for (int i = 0; i < 4; ++i) { xa[i] = (float)c0.h[i]; xa[4 + i] = (float)c1.h[i]; }
  }
  if (BB == 0) {
    const float* pb = (const float*)xbv + (size_t)row * 512;
    float4 b0 = ((const float4*)pb)[lane];
    float4 b1 = ((const float4*)pb)[lane + 64];
    xb[0] = b0.x; xb[1] = b0.y; xb[2] = b0.z; xb[3] = b0.w;
    xb[4] = b1.x; xb[5] = b1.y; xb[6] = b1.z; xb[7] = b1.w;
  } else {
    const bf16_t* pb = (const bf16_t*)xbv + (size_t)row * 512;
    union { uint2 u; bf16_t h[4]; } c0, c1;
    c0.u = ((const uint2*)pb)[lane];
    c1.u = ((const uint2*)pb)[lane + 64];
#pragma unroll
    for (int i = 0; i < 4; ++i) { xb[i] = (float)c0.h[i]; xb[4 + i] = (float)c1.h[i]; }
  }
  float x[8];
#pragma unroll
  for (int i = 0; i < 8; ++i) x[i] = xa[i] + xb[i];
  float s = 0.f, sq = 0.f;
#pragma unroll
  for (int i = 0; i < 8; ++i) { s += x[i]; sq += x[i] * x[i]; }
#pragma unroll
  for (int off = 1; off < 64; off <<= 1) {
    s += __shfl_xor(s, off);
    sq += __shfl_xor(sq, off);
  }
  float mean = s * (1.f / 512.f);
  float var = sq * (1.f / 512.f) - mean * mean;
  float v = var + 1e-5f;
  float y = 0.5f;
#pragma unroll
  for (int it = 0; it < 3; ++it) y = y * (3.0f - v * y * y) * 0.5f;

  float4 g0 = ((const float4*)gamma)[lane];
  float4 g1 = ((const float4*)gamma)[lane + 64];
  float4 e0 = ((const float4*)beta)[lane];
  float4 e1 = ((const float4*)beta)[lane + 64];
  float o[8];
  o[0] = (x[0] - mean) * y * g0.x + e0.x;
  o[1] = (x[1] - mean) * y * g0.y + e0.y;
  o[2] = (x[2] - mean) * y * g0.z + e0.z;
  o[3] = (x[3] - mean) * y * g0.w + e0.w;
  o[4] = (x[4] - mean) * y * g1.x + e1.x;
  o[5] = (x[5] - mean) * y * g1.y + e1.y;
  o[6] = (x[6] - mean) * y * g1.z + e1.z;
  o[7] = (x[7] - mean) * y * g1.w + e1.w;
  if (outf) {
    float* po = outf + (size_t)row * 512;
    ((float4*)po)[lane]      = make_float4(o[0], o[1], o[2], o[3]);
    ((float4*)po)[lane + 64] = make_float4(o[4], o[5], o[6], o[7]);
  }
  if (outb) {
    bf16_t* pq = outb + (size_t)row * 512;
    union { bf16_t h[4]; uint2 u; } c0, c1;
    c0.h[0] = (bf16_t)o[0]; c0.h[1] = (bf16_t)o[1]; c0.h[2] = (bf16_t)o[2]; c0.h[3] = (bf16_t)o[3];
    c1.h[0] = (bf16_t)o[4]; c1.h[1] = (bf16_t)o[5]; c1.h[2] = (bf16_t)o[6]; c1.h[3] = (bf16_t)o[7];
    ((uint2*)pq)[lane]      = c0.u;
    ((uint2*)pq)[lane + 64] = c1.u;
  }
}

// ---------------------------------------------------------------------------
extern "C" void kernel_launch(void* const* d_in, const int* in_sizes, int n_in,
                              void* d_out, int out_size, void* d_ws, size_t ws_size,
                              hipStream_t stream) {
  const float* x      = (const float*)d_in[0];
  const float* Wq     = (const float*)d_in[1];
  const float* Wk     = (const float*)d_in[2];
  const float* Wv     = (const float*)d_in[3];
  const float* Wo     = (const float*)d_in[4];
  const float* W1     = (const float*)d_in[5];
  const float* W2     = (const float*)d_in[6];
  const float* g1     = (const float*)d_in[7];
  const float* b1     = (const float*)d_in[8];
  const float* g2     = (const float*)d_in[9];
  const float* b2     = (const float*)d_in[10];
  const float* gelu_c = (const float*)d_in[11];
  const float* exp_c  = (const float*)d_in[12];

  const int M = 8192;  // B*T
  const size_t actBF = (size_t)M * 512 * 2;
  char* p = (char*)d_ws;
  auto carve = [&](size_t bytes) {
    void* r = (void*)p;
    p += (bytes + 255) & ~(size_t)255;
    return r;
  };
  bf16_t* x_bf   = (bf16_t*)carve(actBF);
  bf16_t* q_bf   = (bf16_t*)carve(actBF);
  bf16_t* k_bf   = (bf16_t*)carve(actBF);
  bf16_t* vT_bf  = (bf16_t*)carve(actBF);
  bf16_t* o_bf   = (bf16_t*)carve(actBF);
  bf16_t* h_bf   = (bf16_t*)carve(actBF);
  bf16_t* proj_bf = (bf16_t*)carve(actBF);  // Wo output (bf16)
  bf16_t* f2_bf  = (bf16_t*)carve(actBF);   // FFN2 output (bf16)
  bf16_t* WqkvT  = (bf16_t*)carve((size_t)1536 * 512 * 2);
  bf16_t* WoT    = (bf16_t*)carve(512 * 512 * 2);
  bf16_t* W1T    = (bf16_t*)carve(512 * 2048 * 2);
  bf16_t* W2T    = (bf16_t*)carve(512 * 2048 * 2);
  bf16_t* g_bf   = (bf16_t*)carve((size_t)M * 2048 * 2);  // 32 MiB
  float*  rsb    = (float*)carve(2 * 65536 * 4);          // rsum partials
  bf16_t* part   = (bf16_t*)g_bf;   // split-K o-partials (dead until FFN1)

  // merged prep: cvt (4096 blocks) + 6 transposes (768 blocks)
  k_prep<<<4864, 256, 0, stream>>>(x, x_bf, Wq, Wk, Wv, Wo, W1, W2,
                                   WqkvT, WoT, W1T, W2T);

  // fused QKV projection, 2-phase (768 blocks — best measured config)
  k_gemm_bt<5, 128><<<dim3(64, 12), 256, 0, stream>>>(
      x_bf, WqkvT, q_bf, k_bf, vT_bf, M, 1536, 512, nullptr);

  // attention (single pass, split-K x2 -> 1024 blocks, bf16 partials)
  k_attn<<<1024, 256, 0, stream>>>(q_bf, k_bf, vT_bf, part, rsb, exp_c);

  // combine partials -> o_bf
  k_combine<<<2048, 256, 0, stream>>>(part, rsb, o_bf);

  // output projection -> bf16 proj
  k_gemm_bt<1, 64><<<dim3(128, 4), 256, 0, stream>>>(
      o_bf, WoT, proj_bf, nullptr, nullptr, M, 512, 512, nullptr);

  // LN1: h = LN(x_fp32 + proj_bf16) -> bf16
  k_ln<0, 1><<<2048, 256, 0, stream>>>(x, proj_bf, g1, b1, nullptr, h_bf);

  // FFN1: gelu(h @ W1) -> bf16, 8-phase 256x256 (256 blocks, 128 KB LDS)
  k_ffn1<<<dim3(32, 8), 512, 131072, stream>>>(h_bf, W1T, g_bf, gelu_c);

  // FFN2 -> bf16 f2
  k_gemm_bt<1, 64><<<dim3(128, 4), 256, 0, stream>>>(
      g_bf, W2T, f2_bf, nullptr, nullptr, M, 512, 2048, nullptr);

  // LN2: out = LN(h_bf16 + f2_bf16) -> fp32
  k_ln<1, 1><<<2048, 256, 0, stream>>>(h_bf, f2_bf, g2, b2, (float*)d_out, nullptr);
}

// Round 21
// 177.381 us; speedup vs baseline: 1.0947x; 1.0150x over previous
//
#include <hip/hip_runtime.h>
#include <hip/hip_bf16.h>

typedef __bf16 bf16_t;
typedef __bf16 bf16x8 __attribute__((ext_vector_type(8)));
typedef float f32x4 __attribute__((ext_vector_type(4)));

#define MFMA16(a, b, c) __builtin_amdgcn_mfma_f32_16x16x32_bf16((a), (b), (c), 0, 0, 0)

__device__ __forceinline__ void gl_lds16(const bf16_t* g, bf16_t* l) {
  __builtin_amdgcn_global_load_lds(
      (const __attribute__((address_space(1))) void*)g,
      (__attribute__((address_space(3))) void*)l, 16, 0, 0);
}

__device__ __forceinline__ unsigned pack_bf16(float a, float b) {
  union { bf16_t h[2]; unsigned u; } c;
  c.h[0] = (bf16_t)a; c.h[1] = (bf16_t)b;
  return c.u;
}

// B=4, T=2048, D=512, H=8, DH=64 — hardcoded
// ---------------------------------------------------------------------------
// Merged prep: blocks [0,4096) convert x -> bf16; blocks [4096,4864) transpose
// the six weight matrices (fp32 -> bf16, LDS tile, coalesced both sides).
__global__ __launch_bounds__(256) void k_prep(
    const float* __restrict__ x, bf16_t* __restrict__ x_bf,
    const float* __restrict__ Wq, const float* __restrict__ Wk,
    const float* __restrict__ Wv, const float* __restrict__ Wo,
    const float* __restrict__ W1, const float* __restrict__ W2,
    bf16_t* __restrict__ WqkvT, bf16_t* __restrict__ WoT,
    bf16_t* __restrict__ W1T, bf16_t* __restrict__ W2T) {
  __shared__ float tile[64][65];
  int bid = blockIdx.x, tid = threadIdx.x;
  if (bid < 4096) {
    int i = bid * 256 + tid;  // 4096*256 == 8192*512/4 exactly
    float4 f = ((const float4*)x)[i];
    union { bf16_t h[4]; uint2 u; } cv;
    cv.h[0] = (bf16_t)f.x; cv.h[1] = (bf16_t)f.y;
    cv.h[2] = (bf16_t)f.z; cv.h[3] = (bf16_t)f.w;
    ((uint2*)x_bf)[i] = cv.u;
    return;
  }
  int t = bid - 4096;
  const float* W; bf16_t* WT; int K, N, idx, gx;
  if (t < 64)       { W = Wq; WT = WqkvT;                      K = 512;  N = 512;  idx = t;       gx = 8;  }
  else if (t < 128) { W = Wk; WT = WqkvT + (size_t)512 * 512;  K = 512;  N = 512;  idx = t - 64;  gx = 8;  }
  else if (t < 192) { W = Wv; WT = WqkvT + (size_t)1024 * 512; K = 512;  N = 512;  idx = t - 128; gx = 8;  }
  else if (t < 256) { W = Wo; WT = WoT;                        K = 512;  N = 512;  idx = t - 192; gx = 8;  }
  else if (t < 512) { W = W1; WT = W1T;                        K = 512;  N = 2048; idx = t - 256; gx = 8;  }
  else              { W = W2; WT = W2T;                        K = 2048; N = 512;  idx = t - 512; gx = 32; }
  int bk = (idx % gx) * 64, bn = (idx / gx) * 64;
  int tx = tid & 63, ty = tid >> 6;
  for (int i = ty; i < 64; i += 4)
    tile[i][tx] = W[(size_t)(bk + i) * N + bn + tx];
  __syncthreads();
  for (int i = ty; i < 64; i += 4)
    WT[(size_t)(bn + i) * K + bk + tx] = (bf16_t)tile[tx][i];
}

// ---------------------------------------------------------------------------
// C[M][N] = A[M][K] @ Bt[N][K]^T, bf16 in, fp32 accum. 2-phase double-buffered
// global_load_lds staging.
// MODE 1: bf16 C
// MODE 5: fused QKV scatter (Q pre-scaled 1/8, K pre-XOR-swizzled, V permuted)
// MODE 6: Wo with FUSED split-K combine: A = (part0+part1)/(r0+r1), reg-staged
//         (A points at part ks=0; part ks=1 at A + 8192*512; rsb via coef).
template <int MODE, int BM>
__global__ __launch_bounds__(256) void k_gemm_bt(
    const bf16_t* __restrict__ A, const bf16_t* __restrict__ Bt,
    bf16_t* __restrict__ Cb, bf16_t* __restrict__ Cb2,
    bf16_t* __restrict__ Cb3,
    int M, int N, int K, const float* __restrict__ coef) {
  __shared__ __align__(16) bf16_t As[2][BM * 32];
  __shared__ __align__(16) bf16_t Bs[2][128 * 32];
  constexpr int NF = (BM == 128) ? 4 : 2;
  int tid = threadIdx.x;
  int lane = tid & 63, wave = tid >> 6;
  int bm = blockIdx.x * BM, bn = blockIdx.y * 128;
  int wr = (BM == 128) ? (wave >> 1) * 64 : 0;
  int wc = (BM == 128) ? (wave & 1) * 64 : wave * 32;
  int lr = lane & 15, lk = (lane >> 4) * 8;
  int srow = tid >> 2, scol = (tid & 3) * 8;

  f32x4 zero = {0.f, 0.f, 0.f, 0.f};
  f32x4 acc[4][NF];
#pragma unroll
  for (int m = 0; m < 4; ++m)
#pragma unroll
    for (int n = 0; n < NF; ++n) acc[m][n] = zero;

  const bf16_t* pA = A + (size_t)(bm + srow) * K + scol;
  const bf16_t* pB = Bt + (size_t)(bn + srow) * K + scol;
  // MODE 6 extras: second partial + per-(row,head) rsum base
  const bf16_t* pA2 = pA + (size_t)8192 * 512;
  const float* rsb = coef;
  int ridx_base = (bm + srow) * 8;

  auto STAGE = [&](int buf, int k0) {
    bf16_t* lA = &As[buf][tid * 8];
    bf16_t* lB = &Bs[buf][tid * 8];
    if (MODE == 6) {
      bf16x8 a0 = *(const bf16x8*)(pA + k0);
      bf16x8 a1 = *(const bf16x8*)(pA2 + k0);
      int h = (k0 + scol) >> 6;
      float r = rsb[ridx_base + h] + rsb[65536 + ridx_base + h];
      float rinv = 1.0f / r;
      bf16x8 o;
#pragma unroll
      for (int i = 0; i < 8; ++i)
        o[i] = (bf16_t)(((float)a0[i] + (float)a1[i]) * rinv);
      *(bf16x8*)lA = o;
    } else {
      gl_lds16(pA + k0, lA);
      if (BM == 128) gl_lds16(pA + (size_t)64 * K + k0, lA + 2048);
    }
    gl_lds16(pB + k0, lB);
    gl_lds16(pB + (size_t)64 * K + k0, lB + 2048);
  };

  STAGE(0, 0);
  __syncthreads();
  int buf = 0;
  for (int k0 = 0; k0 < K; k0 += 32) {
    if (k0 + 32 < K) STAGE(buf ^ 1, k0 + 32);
    bf16x8 a[4], b[NF];
#pragma unroll
    for (int m = 0; m < 4; ++m) a[m] = *(const bf16x8*)&As[buf][(wr + m * 16 + lr) * 32 + lk];
#pragma unroll
    for (int n = 0; n < NF; ++n) b[n] = *(const bf16x8*)&Bs[buf][(wc + n * 16 + lr) * 32 + lk];
    __builtin_amdgcn_s_setprio(1);
#pragma unroll
    for (int m = 0; m < 4; ++m)
#pragma unroll
      for (int n = 0; n < NF; ++n)
        acc[m][n] = MFMA16(a[m], b[n], acc[m][n]);
    __builtin_amdgcn_s_setprio(0);
    __syncthreads();
    buf ^= 1;
  }

  int rbase = (lane >> 4) * 4;
#pragma unroll
  for (int m = 0; m < 4; ++m) {
#pragma unroll
    for (int n = 0; n < NF; ++n) {
#pragma unroll
      for (int r = 0; r < 4; ++r) {
        int gm = bm + wr + m * 16 + rbase + r;
        int gn = bn + wc + n * 16 + lr;
        float v = acc[m][n][r];
        if (MODE == 1 || MODE == 6) {
          Cb[(size_t)gm * N + gn] = (bf16_t)v;
        } else {  // 5: fused QKV scatter with attention-ready layouts
          int mat = gn >> 9, col = gn & 511;
          int b_ = gm >> 11, t_ = gm & 2047, h_ = col >> 6, d_ = col & 63;
          if (mat == 0) {
            Cb[(((size_t)b_ * 8 + h_) * 2048 + t_) * 64 + d_] = (bf16_t)(v * 0.125f);
          } else if (mat == 1) {
            int dsw = d_ ^ ((t_ & 7) << 3);
            Cb2[(((size_t)b_ * 8 + h_) * 2048 + t_) * 64 + dsw] = (bf16_t)v;
          } else {
            int tw = t_ & 63;
            int j = (((tw >> 2) & 3) << 1) | ((tw >> 4) & 1);
            int phys = (((tw & 32) << 1) + (j << 3) + ((tw & 3) << 1)) ^ ((d_ & 7) << 4);
            size_t e = ((((size_t)b_ * 8 + h_) * 64 + d_) * 4096 +
                        (size_t)(t_ >> 6) * 128 + phys) >> 1;
            Cb3[e] = (bf16_t)v;
          }
        }
      }
    }
  }
}

// ---------------------------------------------------------------------------
// FFN1 as 8-phase 256x256 GEMM (T3+T4): C[8192][2048] = gelu(A[8192][512] @
// W1T[2048][512]^T). BK=64 split into two K-halves of 32; LDS = 2 slots x
// {A,B} x 2 kh x [256][32] bf16 = 128 KB (dynamic). 8 waves (2M x 4N), wave
// output 128x64, acc[8][4]. Each phase: 8 ds_read_b128 + one half DMA ->
// raw s_barrier -> 16 MFMA -> barrier; counted vmcnt(6) at odd phases only.
__global__ __launch_bounds__(512, 2) void k_ffn1(
    const bf16_t* __restrict__ A, const bf16_t* __restrict__ Bt,
    bf16_t* __restrict__ C, const float* __restrict__ coef) {
  extern __shared__ __align__(16) bf16_t ldsraw[];  // 131072 bytes
  int tid = threadIdx.x;
  int lane = tid & 63, wave = tid >> 6;
  int wm = wave >> 2, wn = wave & 3;
  int lr = lane & 15, lg = lane >> 4;
  int bm = blockIdx.x * 256, bn = blockIdx.y * 256;

  f32x4 zero = {0.f, 0.f, 0.f, 0.f};
  f32x4 acc[8][4];
#pragma unroll
  for (int a = 0; a < 8; ++a)
#pragma unroll
    for (int n = 0; n < 4; ++n) acc[a][n] = zero;

  int srow = tid >> 2, scol = (tid & 3) * 8;
  const bf16_t* gA = A + (size_t)(bm + srow) * 512 + scol;
  const bf16_t* gB = Bt + (size_t)(bn + srow) * 512 + scol;

  auto LBASE = [&](int slot, int op, int kh) -> bf16_t* {
    return ldsraw + (size_t)((((slot << 1) | op) << 1) | kh) * 8192;
  };
  auto STG = [&](int slot, int op, int kh, int kt) {
    if (kt >= 8) return;
    bf16_t* dst = LBASE(slot, op, kh) + tid * 8;
    const bf16_t* src = (op ? gB : gA) + kt * 64 + kh * 32;
    gl_lds16(src, dst);
    gl_lds16(src + (size_t)128 * 512, dst + 4096);
  };

  auto PH = [&](int slot, int kh, int qm, int sS, int sOp, int sKh, int sT, bool vm) {
    bf16x8 af[4], bb[4];
    const bf16_t* Abase = LBASE(slot, 0, kh);
    const bf16_t* Bbase = LBASE(slot, 1, kh);
#pragma unroll
    for (int mf = 0; mf < 4; ++mf) {
      int r = wm * 128 + qm * 64 + mf * 16 + lr;
      af[mf] = *(const bf16x8*)&Abase[r * 32 + lg * 8];
    }
#pragma unroll
    for (int nf = 0; nf < 4; ++nf) {
      int r = wn * 64 + nf * 16 + lr;
      bb[nf] = *(const bf16x8*)&Bbase[r * 32 + lg * 8];
    }
    STG(sS, sOp, sKh, sT);
    if (vm) __asm__ volatile("s_waitcnt vmcnt(6)" ::: "memory");
    __asm__ volatile("" ::: "memory");
    __builtin_amdgcn_s_barrier();
    __asm__ volatile("" ::: "memory");
    __builtin_amdgcn_s_setprio(1);
#pragma unroll
    for (int mf = 0; mf < 4; ++mf)
#pragma unroll
      for (int nf = 0; nf < 4; ++nf)
        acc[qm * 4 + mf][nf] = MFMA16(af[mf], bb[nf], acc[qm * 4 + mf][nf]);
    __builtin_amdgcn_s_setprio(0);
    __asm__ volatile("" ::: "memory");
    __builtin_amdgcn_s_barrier();
    __asm__ volatile("" ::: "memory");
  };

  // prologue: tile0 full + tile1 kh0; counted wait
  STG(0, 0, 0, 0); STG(0, 1, 0, 0); STG(0, 0, 1, 0); STG(0, 1, 1, 0);
  STG(1, 0, 0, 1); STG(1, 1, 0, 1);
  __asm__ volatile("s_waitcnt vmcnt(8)" ::: "memory");
  __builtin_amdgcn_s_barrier();
  __asm__ volatile("" ::: "memory");

#pragma unroll
  for (int i = 0; i < 4; ++i) {
    int t1 = 2 * i + 1;
    PH(0, 0, 0, 1, 0, 1, t1, false);
    PH(0, 0, 1, 1, 1, 1, t1, true);
    PH(0, 1, 0, 0, 0, 0, t1 + 1, false);
    PH(0, 1, 1, 0, 1, 0, t1 + 1, true);
    PH(1, 0, 0, 0, 0, 1, t1 + 1, false);
    PH(1, 0, 1, 0, 1, 1, t1 + 1, true);
    PH(1, 1, 0, 1, 0, 0, t1 + 2, false);
    PH(1, 1, 1, 1, 1, 0, t1 + 2, true);
  }

  // epilogue: iterative-power GELU poly (matches reference eval order), bf16
  float c8[8];
#pragma unroll
  for (int q = 0; q < 8; ++q) c8[q] = coef[q];
#pragma unroll
  for (int am = 0; am < 8; ++am) {
    int qm = am >> 2, mf = am & 3;
#pragma unroll
    for (int nf = 0; nf < 4; ++nf)
#pragma unroll
      for (int rr = 0; rr < 4; ++rr) {
        int row = bm + wm * 128 + qm * 64 + mf * 16 + lg * 4 + rr;
        int col = bn + wn * 64 + nf * 16 + lr;
        float v = acc[am][nf][rr];
        float xx = fminf(fmaxf(v, -4.f), 4.f);
        float pw = 1.f, pp = c8[0];
#pragma unroll
        for (int q2 = 1; q2 < 8; ++q2) { pw *= xx; pp += c8[q2] * pw; }
        C[(size_t)row * 2048 + col] = (bf16_t)pp;
      }
  }
}

// ---------------------------------------------------------------------------
// SINGLE-PASS attention, SPLIT-K (KS=2). QBLK=128, 4 waves, j=2 reuse,
// K/V 2-deep DMA rings, ONE barrier per kt, Horner-only softmax (clamp
// provably dead), rsum on the MFMA pipe. bf16 o-partials + fp32 rsum partials.
__global__ __launch_bounds__(256, 4) void k_attn(
    const bf16_t* __restrict__ qb, const bf16_t* __restrict__ kb,
    const bf16_t* __restrict__ vtb, bf16_t* __restrict__ part,
    float* __restrict__ rsb, const float* __restrict__ exp_c) {
  __shared__ __align__(16) bf16_t Ks[2][64 * 64];
  __shared__ __align__(16) bf16_t Vs[2][64 * 64];
  int tid = threadIdx.x, lane = tid & 63, wave = tid >> 6;
  int b0 = blockIdx.x;
  int bid = (b0 & 7) * 128 + (b0 >> 3);  // XCD-chunked (1024 % 8 == 0)
  int ks = bid & 1, qt = (bid >> 1) & 15, bh = bid >> 5;
  int kt0 = ks * 16;
  const size_t bho = (size_t)bh * (2048 * 64);
  const bf16_t* Q = qb + bho + (size_t)qt * 128 * 64;  // pre-scaled by 1/8
  const bf16_t* Kp = kb + bho;   // rows pre-XOR-swizzled
  const bf16_t* Vp = vtb + bho;  // gl_lds-linear permuted [64 dh][2048 t]
  int lr = lane & 15, lg = lane >> 4;

  bf16x8 qa[2][2];
#pragma unroll
  for (int j = 0; j < 2; ++j)
#pragma unroll
    for (int h = 0; h < 2; ++h)
      qa[j][h] = *(const bf16x8*)&Q[(wave * 32 + j * 16 + lr) * 64 + h * 32 + lg * 8];

  float ec[7];
#pragma unroll
  for (int i = 0; i < 7; ++i) ec[i] = exp_c[i];

  union { unsigned u[4]; bf16x8 v; } ones;
#pragma unroll
  for (int i = 0; i < 4; ++i) ones.u[i] = 0x3f803f80u;  // bf16 1.0 x2

  int offA[4], offB[4];
#pragma unroll
  for (int n = 0; n < 4; ++n) {
    int row = n * 16 + lr, sw = (row & 7) << 4;
    offA[n] = (row * 128 + lg * 16) ^ sw;
    offB[n] = (row * 128 + 64 + lg * 16) ^ sw;
  }

  auto STAGE_K = [&](int buf, int kt) {
    bf16_t* lk = &Ks[buf][tid * 8];
    const bf16_t* gk = Kp + (size_t)kt * 4096 + tid * 8;
    gl_lds16(gk, lk);
    gl_lds16(gk + 2048, lk + 2048);
  };
  auto STAGE_V = [&](int buf, int kt) {
    bf16_t* lv = &Vs[buf][tid * 8];
    const bf16_t* gv = Vp + (size_t)(tid >> 3) * 2048 + kt * 64 + (tid & 7) * 8;
    gl_lds16(gv, lv);
    gl_lds16(gv + (size_t)32 * 2048, lv + 2048);
  };

  f32x4 zero = {0.f, 0.f, 0.f, 0.f};
  f32x4 oacc[2][4], oacc_s[2];
#pragma unroll
  for (int j = 0; j < 2; ++j) {
#pragma unroll
    for (int n = 0; n < 4; ++n) oacc[j][n] = zero;
    oacc_s[j] = zero;
  }

  STAGE_K(0, kt0);
  STAGE_V(0, kt0);
  __syncthreads();

  for (int lt = 0; lt < 16; ++lt) {
    if (lt < 15) {
      STAGE_K((lt + 1) & 1, kt0 + lt + 1);
      STAGE_V((lt + 1) & 1, kt0 + lt + 1);
    }
    const char* kbase = (const char*)Ks[lt & 1];
    const char* vbase = (const char*)Vs[lt & 1];
    f32x4 s[2][4];
    __builtin_amdgcn_s_setprio(1);
#pragma unroll
    for (int n = 0; n < 4; ++n) {
      bf16x8 kb0 = *(const bf16x8*)(kbase + offA[n]);
      bf16x8 kb1 = *(const bf16x8*)(kbase + offB[n]);
#pragma unroll
      for (int j = 0; j < 2; ++j)
        s[j][n] = MFMA16(kb1, qa[j][1], MFMA16(kb0, qa[j][0], zero));
    }
    __builtin_amdgcn_s_setprio(0);
    union { unsigned u[4]; bf16x8 v; } pa[2][2];
#pragma unroll
    for (int j = 0; j < 2; ++j) {
      unsigned pk[4][2];
#pragma unroll
      for (int n = 0; n < 4; ++n) {
        float pf[4];
#pragma unroll
        for (int r = 0; r < 4; ++r) {
          float xv = s[j][n][r];  // scores pre-scaled via Q*0.125
          float p = ec[6];
#pragma unroll
          for (int i = 5; i >= 0; --i) p = __builtin_fmaf(p, xv, ec[i]);
          pf[r] = p;
        }
        pk[n][0] = pack_bf16(pf[0], pf[1]);
        pk[n][1] = pack_bf16(pf[2], pf[3]);
      }
      pa[j][0].u[0] = pk[0][0]; pa[j][0].u[1] = pk[0][1];
      pa[j][0].u[2] = pk[1][0]; pa[j][0].u[3] = pk[1][1];
      pa[j][1].u[0] = pk[2][0]; pa[j][1].u[1] = pk[2][1];
      pa[j][1].u[2] = pk[3][0]; pa[j][1].u[3] = pk[3][1];
    }
    __builtin_amdgcn_s_setprio(1);
#pragma unroll
    for (int dd = 0; dd < 4; ++dd) {
      bf16x8 v0 = *(const bf16x8*)(vbase + offA[dd]);
      bf16x8 v1 = *(const bf16x8*)(vbase + offB[dd]);
#pragma unroll
      for (int j = 0; j < 2; ++j)
        oacc[j][dd] = MFMA16(pa[j][1].v, v1, MFMA16(pa[j][0].v, v0, oacc[j][dd]));
    }
#pragma unroll
    for (int j = 0; j < 2; ++j)
      oacc_s[j] = MFMA16(pa[j][1].v, ones.v, MFMA16(pa[j][0].v, ones.v, oacc_s[j]));
    __builtin_amdgcn_s_setprio(0);
    __syncthreads();
  }

  bf16_t* pp = part + (size_t)ks * (8192 * 512);
  int b_ = bh >> 3, h_ = bh & 7;
#pragma unroll
  for (int j = 0; j < 2; ++j) {
#pragma unroll
    for (int dd = 0; dd < 4; ++dd)
#pragma unroll
      for (int r = 0; r < 4; ++r) {
        int t_ = qt * 128 + wave * 32 + j * 16 + lg * 4 + r;
        int d_ = dd * 16 + lr;
        pp[(((size_t)b_ * 2048 + t_) * 8 + h_) * 64 + d_] = (bf16_t)oacc[j][dd][r];
      }
    if (lr == 0) {
#pragma unroll
      for (int r = 0; r < 4; ++r) {
        int t_ = qt * 128 + wave * 32 + j * 16 + lg * 4 + r;
        rsb[ks * 65536 + ((b_ * 2048 + t_) * 8 + h_)] = oacc_s[j][r];
      }
    }
  }
}

// ---------------------------------------------------------------------------
// Fused residual + LayerNorm (replicates Newton rsqrt exactly: 3 iters from
// 0.5). AB/BB select fp32(0)/bf16(1) for the two inputs.
template <int AB, int BB>
__global__ __launch_bounds__(256) void k_ln(
    const void* __restrict__ xav, const void* __restrict__ xbv,
    const float* __restrict__ gamma, const float* __restrict__ beta,
    float* __restrict__ outf, bf16_t* __restrict__ outb) {
  int row = blockIdx.x * 4 + (threadIdx.x >> 6);
  int lane = threadIdx.x & 63;
  float xa[8], xb[8];
  if (AB == 0) {
    const float* pa = (const float*)xav + (size_t)row * 512;
    float4 a0 = ((const float4*)pa)[lane];
    float4 a1 = ((const float4*)pa)[lane + 64];
    xa[0] = a0.x; xa[1] = a0.y; xa[2] = a0.z; xa[3] = a0.w;
    xa[4] = a1.x; xa[5] = a1.y; xa[6] = a1.z; xa[7] = a1.w;
  } else {
    const bf16_t* pa = (const bf16_t*)xav + (size_t)row * 512;
    union { uint2 u; bf16_t h[4]; } c0, c1;
    c0.u = ((const uint2*)pa)[lane];
    c1.u = ((const uint2*)pa)[lane + 64];
#pragma unroll
    for (int i = 0; i < 4; ++i) { xa[i] = (float)c0.h[i]; xa[4 + i] = (float)c1.h[i]; }
  }
  if (BB == 0) {
    const float* pb = (const float*)xbv + (size_t)row * 512;
    float4 b0 = ((const float4*)pb)[lane];
    float4 b1 = ((const float4*)pb)[lane + 64];
    xb[0] = b0.x; xb[1] = b0.y; xb[2] = b0.z; xb[3] = b0.w;
    xb[4] = b1.x; xb[5] = b1.y; xb[6] = b1.z; xb[7] = b1.w;
  } else {
    const bf16_t* pb = (const bf16_t*)xbv + (size_t)row * 512;
    union { uint2 u; bf16_t h[4]; } c0, c1;
    c0.u = ((const uint2*)pb)[lane];
    c1.u = ((const uint2*)pb)[lane + 64];
#pragma unroll
    for (int i = 0; i < 4; ++i) { xb[i] = (float)c0.h[i]; xb[4 + i] = (float)c1.h[i]; }
  }
  float x[8];
#pragma unroll
  for (int i = 0; i < 8; ++i) x[i] = xa[i] + xb[i];
  float s = 0.f, sq = 0.f;
#pragma unroll
  for (int i = 0; i < 8; ++i) { s += x[i]; sq += x[i] * x[i]; }
#pragma unroll
  for (int off = 1; off < 64; off <<= 1) {
    s += __shfl_xor(s, off);
    sq += __shfl_xor(sq, off);
  }
  float mean = s * (1.f / 512.f);
  float var = sq * (1.f / 512.f) - mean * mean;
  float v = var + 1e-5f;
  float y = 0.5f;
#pragma unroll
  for (int it = 0; it < 3; ++it) y = y * (3.0f - v * y * y) * 0.5f;

  float4 g0 = ((const float4*)gamma)[lane];
  float4 g1 = ((const float4*)gamma)[lane + 64];
  float4 e0 = ((const float4*)beta)[lane];
  float4 e1 = ((const float4*)beta)[lane + 64];
  float o[8];
  o[0] = (x[0] - mean) * y * g0.x + e0.x;
  o[1] = (x[1] - mean) * y * g0.y + e0.y;
  o[2] = (x[2] - mean) * y * g0.z + e0.z;
  o[3] = (x[3] - mean) * y * g0.w + e0.w;
  o[4] = (x[4] - mean) * y * g1.x + e1.x;
  o[5] = (x[5] - mean) * y * g1.y + e1.y;
  o[6] = (x[6] - mean) * y * g1.z + e1.z;
  o[7] = (x[7] - mean) * y * g1.w + e1.w;
  if (outf) {
    float* po = outf + (size_t)row * 512;
    ((float4*)po)[lane]      = make_float4(o[0], o[1], o[2], o[3]);
    ((float4*)po)[lane + 64] = make_float4(o[4], o[5], o[6], o[7]);
  }
  if (outb) {
    bf16_t* pq = outb + (size_t)row * 512;
    union { bf16_t h[4]; uint2 u; } c0, c1;
    c0.h[0] = (bf16_t)o[0]; c0.h[1] = (bf16_t)o[1]; c0.h[2] = (bf16_t)o[2]; c0.h[3] = (bf16_t)o[3];
    c1.h[0] = (bf16_t)o[4]; c1.h[1] = (bf16_t)o[5]; c1.h[2] = (bf16_t)o[6]; c1.h[3] = (bf16_t)o[7];
    ((uint2*)pq)[lane]      = c0.u;
    ((uint2*)pq)[lane + 64] = c1.u;
  }
}

// ---------------------------------------------------------------------------
extern "C" void kernel_launch(void* const* d_in, const int* in_sizes, int n_in,
                              void* d_out, int out_size, void* d_ws, size_t ws_size,
                              hipStream_t stream) {
  const float* x      = (const float*)d_in[0];
  const float* Wq     = (const float*)d_in[1];
  const float* Wk     = (const float*)d_in[2];
  const float* Wv     = (const float*)d_in[3];
  const float* Wo     = (const float*)d_in[4];
  const float* W1     = (const float*)d_in[5];
  const float* W2     = (const float*)d_in[6];
  const float* g1     = (const float*)d_in[7];
  const float* b1     = (const float*)d_in[8];
  const float* g2     = (const float*)d_in[9];
  const float* b2     = (const float*)d_in[10];
  const float* gelu_c = (const float*)d_in[11];
  const float* exp_c  = (const float*)d_in[12];

  const int M = 8192;  // B*T
  const size_t actBF = (size_t)M * 512 * 2;
  char* p = (char*)d_ws;
  auto carve = [&](size_t bytes) {
    void* r = (void*)p;
    p += (bytes + 255) & ~(size_t)255;
    return r;
  };
  bf16_t* x_bf   = (bf16_t*)carve(actBF);
  bf16_t* q_bf   = (bf16_t*)carve(actBF);
  bf16_t* k_bf   = (bf16_t*)carve(actBF);
  bf16_t* vT_bf  = (bf16_t*)carve(actBF);
  bf16_t* h_bf   = (bf16_t*)carve(actBF);
  bf16_t* proj_bf = (bf16_t*)carve(actBF);  // Wo output (bf16)
  bf16_t* f2_bf  = (bf16_t*)carve(actBF);   // FFN2 output (bf16)
  bf16_t* WqkvT  = (bf16_t*)carve((size_t)1536 * 512 * 2);
  bf16_t* WoT    = (bf16_t*)carve(512 * 512 * 2);
  bf16_t* W1T    = (bf16_t*)carve(512 * 2048 * 2);
  bf16_t* W2T    = (bf16_t*)carve(512 * 2048 * 2);
  bf16_t* g_bf   = (bf16_t*)carve((size_t)M * 2048 * 2);  // 32 MiB
  float*  rsb    = (float*)carve(2 * 65536 * 4);          // rsum partials
  bf16_t* part   = (bf16_t*)g_bf;   // split-K o-partials (dead until FFN1)

  // merged prep: cvt (4096 blocks) + 6 transposes (768 blocks)
  k_prep<<<4864, 256, 0, stream>>>(x, x_bf, Wq, Wk, Wv, Wo, W1, W2,
                                   WqkvT, WoT, W1T, W2T);

  // fused QKV projection, 2-phase (768 blocks — best measured config)
  k_gemm_bt<5, 128><<<dim3(64, 12), 256, 0, stream>>>(
      x_bf, WqkvT, q_bf, k_bf, vT_bf, M, 1536, 512, nullptr);

  // attention (single pass, split-K x2 -> 1024 blocks, bf16 partials)
  k_attn<<<1024, 256, 0, stream>>>(q_bf, k_bf, vT_bf, part, rsb, exp_c);

  // output projection with FUSED split-K combine (A = (p0+p1)/r, reg-staged)
  k_gemm_bt<6, 64><<<dim3(128, 4), 256, 0, stream>>>(
      part, WoT, proj_bf, nullptr, nullptr, M, 512, 512, rsb);

  // LN1: h = LN(x_fp32 + proj_bf16) -> bf16
  k_ln<0, 1><<<2048, 256, 0, stream>>>(x, proj_bf, g1, b1, nullptr, h_bf);

  // FFN1: gelu(h @ W1) -> bf16, 8-phase 256x256 (256 blocks, 128 KB LDS)
  k_ffn1<<<dim3(32, 8), 512, 131072, stream>>>(h_bf, W1T, g_bf, gelu_c);

  // FFN2 -> bf16 f2
  k_gemm_bt<1, 64><<<dim3(128, 4), 256, 0, stream>>>(
      g_bf, W2T, f2_bf, nullptr, nullptr, M, 512, 2048, nullptr);

  // LN2: out = LN(h_bf16 + f2_bf16) -> fp32
  k_ln<1, 1><<<2048, 256, 0, stream>>>(h_bf, f2_bf, g2, b2, (float*)d_out, nullptr);
}